// Round 1
// baseline (768.131 us; speedup 1.0000x reference)
//
#include <hip/hip_runtime.h>

// Problem constants (B,T,HID)=(4,2048,2048), heads 16, kv 2, hd 128.
#define B_    4
#define T_    2048
#define HID_  2048
#define NH_   16
#define NKV_  2
#define HD_   128
#define M_    (B_ * T_)      // 8192 rows
#define NQKV_ 2560           // 16*128 + 2*128 + 2*128

typedef __bf16 bf16x8 __attribute__((ext_vector_type(8)));
typedef float  f32x4  __attribute__((ext_vector_type(4)));

#define AS1 __attribute__((address_space(1)))
#define AS3 __attribute__((address_space(3)))

#if __has_builtin(__builtin_amdgcn_exp2f)
#define EXP2(x) __builtin_amdgcn_exp2f(x)
#else
#define EXP2(x) exp2f(x)
#endif

// async global->LDS, 16B per lane; LDS dest = wave-uniform base + lane*16
__device__ __forceinline__ void load_lds16(const void* g, void* l) {
  __builtin_amdgcn_global_load_lds((const AS1 unsigned int*)g,
                                   (AS3 unsigned int*)l, 16, 0, 0);
}

__device__ __forceinline__ unsigned short f2bf(float x) {
  union { float f; unsigned u; } a; a.f = x;
  unsigned r = a.u + 0x7fffu + ((a.u >> 16) & 1u);   // RNE
  return (unsigned short)(r >> 16);
}
__device__ __forceinline__ float bf2f(unsigned h) {
  union { unsigned u; float f; } a; a.u = h << 16;
  return a.f;
}
// pack two fp32 -> u32 of two bf16 (RTZ; P in [0,1], bias negligible)
__device__ __forceinline__ unsigned pk_rtz(float lo, float hi) {
  union { float f; unsigned u; } a, b; a.f = lo; b.f = hi;
  return (a.u >> 16) | (b.u & 0xffff0000u);
}

// ---------------- cast f32 -> bf16 (4 elems/thread) ----------------
__global__ __launch_bounds__(256) void cast_bf16(const float* __restrict__ in,
                                                 unsigned short* __restrict__ out,
                                                 int n4) {
  int i = blockIdx.x * 256 + threadIdx.x;
  if (i >= n4) return;
  float4 v = ((const float4*)in)[i];
  ushort4 o;
  o.x = f2bf(v.x); o.y = f2bf(v.y); o.z = f2bf(v.z); o.w = f2bf(v.w);
  ((ushort4*)out)[i] = o;
}

// merged Wq|Wk|Wv cast into contiguous wqkv (dest float4-index == i)
__global__ __launch_bounds__(256) void cast_w(const float* __restrict__ Wq,
                                              const float* __restrict__ Wk,
                                              const float* __restrict__ Wv,
                                              unsigned short* __restrict__ out) {
  int i = blockIdx.x * 256 + threadIdx.x;  // 5120*256 = 1310720 exact
  const float* src; int j;
  if (i < 1048576)      { src = Wq; j = i; }
  else if (i < 1179648) { src = Wk; j = i - 1048576; }
  else                  { src = Wv; j = i - 1179648; }
  float4 v = ((const float4*)src)[j];
  ushort4 o;
  o.x = f2bf(v.x); o.y = f2bf(v.y); o.z = f2bf(v.z); o.w = f2bf(v.w);
  ((ushort4*)out)[i] = o;
}

// ---------------- GEMM C = A * B^T (A: MxK row-major bf16, B: NxK row-major bf16)
// m97-style + 16B-unit XOR swizzle by (row>>1)&3 to kill fragment-read bank conflicts.
template <int OUT_BF16>
__global__ __launch_bounds__(256) void gemm_bt(const unsigned short* __restrict__ A,
                                               const unsigned short* __restrict__ Bm,
                                               void* __restrict__ C,
                                               int M, int N, int K) {
  __shared__ __align__(16) unsigned short As[128 * 32];
  __shared__ __align__(16) unsigned short Bs[128 * 32];
  const int tid = threadIdx.x;
  const int w = tid >> 6, lane = tid & 63;
  const int m0 = blockIdx.y << 7, n0 = blockIdx.x << 7;
  const int c = lane & 15, grp = lane >> 4;
  const int lr = lane >> 2;
  const int su = (((lane & 3) ^ ((lr >> 1) & 3)) << 3);   // staging source unit (swizzled)
  const int sw = (c >> 1) & 3;                            // read-side swizzle key
  const int wm = (w & 1) << 6, wn = (w >> 1) << 6;
  f32x4 acc[4][4] = {};
  for (int k0 = 0; k0 < K; k0 += 32) {
    __syncthreads();
    {
      int r0 = w << 4;
      load_lds16(A + (size_t)(m0 + r0 + lr) * K + k0 + su, &As[r0 * 32]);
      load_lds16(A + (size_t)(m0 + 64 + r0 + lr) * K + k0 + su, &As[(64 + r0) * 32]);
      load_lds16(Bm + (size_t)(n0 + r0 + lr) * K + k0 + su, &Bs[r0 * 32]);
      load_lds16(Bm + (size_t)(n0 + 64 + r0 + lr) * K + k0 + su, &Bs[(64 + r0) * 32]);
    }
    __syncthreads();
    bf16x8 af[4], bf[4];
#pragma unroll
    for (int i = 0; i < 4; i++)
      af[i] = *(const bf16x8*)&As[(wm + i * 16 + c) * 32 + ((grp ^ sw) << 3)];
#pragma unroll
    for (int j = 0; j < 4; j++)
      bf[j] = *(const bf16x8*)&Bs[(wn + j * 16 + c) * 32 + ((grp ^ sw) << 3)];
#pragma unroll
    for (int i = 0; i < 4; i++)
#pragma unroll
      for (int j = 0; j < 4; j++)
        acc[i][j] = __builtin_amdgcn_mfma_f32_16x16x32_bf16(af[i], bf[j], acc[i][j], 0, 0, 0);
  }
#pragma unroll
  for (int i = 0; i < 4; i++)
#pragma unroll
    for (int j = 0; j < 4; j++)
#pragma unroll
      for (int r = 0; r < 4; r++) {
        int row = m0 + wm + i * 16 + grp * 4 + r;
        int col = n0 + wn + j * 16 + c;
        float v = acc[i][j][r];
        if (OUT_BF16) ((unsigned short*)C)[(size_t)row * N + col] = f2bf(v);
        else          ((float*)C)[(size_t)row * N + col] = v;
      }
}

// ---------------- RoPE + RMSNorm. One wave per head per (b,t).
// q additionally pre-scaled by attn_scale*log2(e) so flash's softmax uses exp2 directly.
__global__ __launch_bounds__(256) void rope_norm(const unsigned short* __restrict__ qkv,
                                                 const float* __restrict__ cosb,
                                                 const float* __restrict__ sinb,
                                                 unsigned short* __restrict__ qo,
                                                 unsigned short* __restrict__ ko,
                                                 unsigned short* __restrict__ vo) {
  const int m = blockIdx.x;
  const int b = m >> 11, t = m & 2047;
  const int w = threadIdx.x >> 6, lane = threadIdx.x & 63;
  const float cv = cosb[t * 64 + lane], sv = sinb[t * 64 + lane];
  const unsigned short* row = qkv + (size_t)m * NQKV_;
  const float QSCL = 0.08838834764831845f * 1.4426950408889634f;  // 1/sqrt(128)*log2(e)
  for (int hh = w; hh < 20; hh += 4) {
    if (hh < 18) {
      const int col0 = (hh < 16) ? hh * 128 : 2048 + (hh - 16) * 128;
      unsigned pr = *(const unsigned*)(row + col0 + 2 * lane);
      float xr = bf2f(pr & 0xffffu), xi = bf2f(pr >> 16);
      float orr = xr * cv - xi * sv;
      float oi  = xr * sv + xi * cv;
      float ss = orr * orr + oi * oi;
#pragma unroll
      for (int off = 1; off < 64; off <<= 1) ss += __shfl_xor(ss, off);
      float scl = rsqrtf(ss * (1.0f / 128.0f) + 1.1920929e-07f);  // fp32 eps
      if (hh < 16) {
        float s2 = scl * QSCL;
        unsigned out = (unsigned)f2bf(orr * s2) | ((unsigned)f2bf(oi * s2) << 16);
        *(unsigned*)(qo + (((size_t)(b * NH_ + hh)) * T_ + t) * HD_ + 2 * lane) = out;
      } else {
        unsigned out = (unsigned)f2bf(orr * scl) | ((unsigned)f2bf(oi * scl) << 16);
        *(unsigned*)(ko + (((size_t)(b * NKV_ + (hh - 16))) * T_ + t) * HD_ + 2 * lane) = out;
      }
    } else {
      const int gg = hh - 18;
      unsigned pr = *(const unsigned*)(row + 2304 + gg * 128 + 2 * lane);
      *(unsigned*)(vo + (((size_t)(b * NKV_ + gg)) * T_ + t) * HD_ + 2 * lane) = pr;
    }
  }
}

// ---------------- V transpose: (bg, T, HD) -> (bg, HD, T), 64x64 LDS tiles.
// Output columns are PERMUTED within each 32-kv chunk so flash's PV A-fragment
// is one contiguous b128: position p=8g+4a+b holds kv=16a+4g+b.
__global__ __launch_bounds__(256) void transpose_v(const unsigned short* __restrict__ v,
                                                   unsigned short* __restrict__ vt) {
  __shared__ unsigned short tile[64][65];
  const int bg = blockIdx.z;
  const int t0 = blockIdx.x << 6, h0 = blockIdx.y << 6;
  const unsigned short* src = v + (size_t)bg * T_ * HD_;
  unsigned short* dst = vt + (size_t)bg * T_ * HD_;
  const int tid = threadIdx.x;
  const int rr = tid >> 4, cc = (tid & 15) << 2;
  const int u = (cc >> 2) & 7;
  const int cp = (cc & 32) + 16 * (u & 1) + 4 * ((u >> 1) & 3);  // source col for dst col cc
#pragma unroll
  for (int it = 0; it < 4; it++) {
    int r = rr + it * 16;
    ushort4 d = *(const ushort4*)(src + (size_t)(t0 + r) * HD_ + h0 + cc);
    tile[r][cc + 0] = d.x; tile[r][cc + 1] = d.y;
    tile[r][cc + 2] = d.z; tile[r][cc + 3] = d.w;
  }
  __syncthreads();
#pragma unroll
  for (int it = 0; it < 4; it++) {
    int r = rr + it * 16;
    ushort4 d;
    d.x = tile[cp + 0][r]; d.y = tile[cp + 1][r];
    d.z = tile[cp + 2][r]; d.w = tile[cp + 3][r];
    *(ushort4*)(dst + (size_t)(h0 + r) * T_ + t0 + cc) = d;
  }
}

// ---------------- Flash attention v4: S^T form, lane-local P, double-buffered
// 64-kv K chunks in LDS (32 KiB total), V STREAMED from global/L2 (per-(b,g)
// V^T is 512 KB = L2-resident; staging it was pure overhead and capped
// occupancy at 2 blocks/CU). With LDS=32KiB and VGPR<=128 we get 4 blocks/CU
// -> all 1024 blocks resident from t=0 (no dispatch tail).
// Grid is flattened 1D with a balanced tile mapping: each mod-256 residue
// class gets tiles {15-u, u, 15-((u+2)&15), (u+2)&15} whose causal chunk
// counts sum to exactly 68 (the mean) -> no CU-level work imbalance.
__global__ __launch_bounds__(256, 4) void flash_attn(const unsigned short* __restrict__ q,
                                                     const unsigned short* __restrict__ k,
                                                     const unsigned short* __restrict__ vt,
                                                     unsigned short* __restrict__ y) {
  __shared__ __align__(16) unsigned short Kb[2][8192];  // [buf][dc4][kv64][d-unit swz]
  const int tid = threadIdx.x;
  const int w = tid >> 6, lane = tid & 63;
  const int c = lane & 15, grp = lane >> 4;
  const int lr = lane >> 2;
  const int sw = (c >> 1) & 3;
  const int su = (((lane & 3) ^ ((lr >> 1) & 3)) << 3);

  // balanced (tile, head, batch) decode from 1D block id
  const int idx = blockIdx.x;                 // 0..1023
  const int j = idx >> 8;                     // generation 0..3
  const int u = idx & 15;
  const int v = (idx >> 4) & 15;
  const int tp = (u + 2 * (j >> 1)) & 15;
  const int tile_i = (j & 1) ? tp : (15 - tp);  // heavy-first within each gen
  const int t0 = tile_i << 7;
  const int hq = v, b = j, g = hq >> 3;
  const int t0w = t0 + w * 32;

  const unsigned short* qbase = q + (((size_t)(b * NH_ + hq)) * T_ + t0) * HD_;
  const unsigned short* kbase = k + ((size_t)(b * NKV_ + g)) * T_ * HD_;
  const unsigned short* vtbase = vt + ((size_t)(b * NKV_ + g)) * HD_ * T_;
  // per-lane V stream base: row (16h+c) of V^T, unit grp (permutation is
  // pre-baked into vt by transpose_v, so this IS the MFMA A-fragment)
  const unsigned short* vg = vtbase + (size_t)c * T_ + grp * 8;

  // Q fragments (pre-scaled by scale*log2e): B-operand layout, rows q
  bf16x8 qf[2][4];
#pragma unroll
  for (int ti = 0; ti < 2; ti++)
#pragma unroll
    for (int ks = 0; ks < 4; ks++)
      qf[ti][ks] = *(const bf16x8*)(qbase + (size_t)(w * 32 + ti * 16 + c) * HD_ + ks * 32 + grp * 8);

  f32x4 oacc[2][8] = {};            // O^T: row h=hj*16+grp*4+r, col q=ti*16+c
  float mrun[2], lrun[2];
  mrun[0] = mrun[1] = -__builtin_inff();
  lrun[0] = lrun[1] = 0.f;

  auto stage = [&](int s0, int bb) {
    const unsigned short* kp = kbase + (size_t)(s0 + w * 16 + lr) * HD_ + su;
#pragma unroll
    for (int dc = 0; dc < 4; dc++)
      load_lds16(kp + dc * 32, &Kb[bb][dc * 2048 + (w * 16) * 32]);
  };

  const int nch = (t0 >> 6) + 2;
  stage(0, 0);
  __syncthreads();                       // chunk 0 resident
  for (int ic = 0; ic < nch; ic++) {
    const int s0 = ic << 6, bb = ic & 1;
    if (ic + 1 < nch) stage((ic + 1) << 6, bb ^ 1);   // async prefetch, drained at loop-end barrier
    if (s0 <= t0w + 31) {                // wave has unmasked work in this chunk
      const unsigned short* Kc = Kb[bb];
      // S^T = K·Q^T : lane holds P[q=ti*16+c][kv=kvt*16+grp*4+r] (log2 domain)
      f32x4 st[2][4] = {};
#pragma unroll
      for (int s = 0; s < 4; s++)
#pragma unroll
        for (int kvt = 0; kvt < 4; kvt++) {
          bf16x8 ak = *(const bf16x8*)&Kc[s * 2048 + (kvt * 16 + c) * 32 + ((grp ^ sw) << 3)];
          st[0][kvt] = __builtin_amdgcn_mfma_f32_16x16x32_bf16(ak, qf[0][s], st[0][kvt], 0, 0, 0);
          st[1][kvt] = __builtin_amdgcn_mfma_f32_16x16x32_bf16(ak, qf[1][s], st[1][kvt], 0, 0, 0);
        }
      if (s0 + 63 > t0w) {               // diagonal chunk: causal mask
#pragma unroll
        for (int ti = 0; ti < 2; ti++)
#pragma unroll
          for (int kvt = 0; kvt < 4; kvt++)
#pragma unroll
            for (int r = 0; r < 4; r++) {
              int kv = s0 + kvt * 16 + grp * 4 + r;
              int qq = t0w + ti * 16 + c;
              if (kv > qq) st[ti][kvt][r] = -__builtin_inff();
            }
      }
      // online softmax per q-column (lane-local + cross-grp butterfly)
      unsigned pkv[2][4][2];
#pragma unroll
      for (int ti = 0; ti < 2; ti++) {
        float rm = st[ti][0][0];
#pragma unroll
        for (int kvt = 0; kvt < 4; kvt++)
#pragma unroll
          for (int r = 0; r < 4; r++) rm = fmaxf(rm, st[ti][kvt][r]);
        rm = fmaxf(rm, __shfl_xor(rm, 16));
        rm = fmaxf(rm, __shfl_xor(rm, 32));
        float mnew = fmaxf(mrun[ti], rm);
        float alpha = EXP2(mrun[ti] - mnew);
        mrun[ti] = mnew;
        float rs = 0.f;
#pragma unroll
        for (int kvt = 0; kvt < 4; kvt++) {
          float p0 = EXP2(st[ti][kvt][0] - mnew);
          float p1 = EXP2(st[ti][kvt][1] - mnew);
          float p2 = EXP2(st[ti][kvt][2] - mnew);
          float p3 = EXP2(st[ti][kvt][3] - mnew);
          rs += (p0 + p1) + (p2 + p3);
          pkv[ti][kvt][0] = pk_rtz(p0, p1);
          pkv[ti][kvt][1] = pk_rtz(p2, p3);
        }
        rs += __shfl_xor(rs, 16);
        rs += __shfl_xor(rs, 32);
        lrun[ti] = lrun[ti] * alpha + rs;
#pragma unroll
        for (int hj = 0; hj < 8; hj++)
#pragma unroll
          for (int r = 0; r < 4; r++) oacc[ti][hj][r] *= alpha;
      }
      // O^T += V^T·P (k permuted; vt pre-permuted so A-frag is one b128
      // straight from global -- L2-resident, no LDS round-trip)
#pragma unroll
      for (int s = 0; s < 2; s++) {
        union { int4 i; bf16x8 v; } av[8];
#pragma unroll
        for (int hj = 0; hj < 8; hj++)
          av[hj].i = *(const int4*)(vg + (size_t)(hj * 16) * T_ + s0 + s * 32);
        union { int4 i; bf16x8 v; } pf0, pf1;
        pf0.i = make_int4(pkv[0][2 * s][0], pkv[0][2 * s][1], pkv[0][2 * s + 1][0], pkv[0][2 * s + 1][1]);
        pf1.i = make_int4(pkv[1][2 * s][0], pkv[1][2 * s][1], pkv[1][2 * s + 1][0], pkv[1][2 * s + 1][1]);
#pragma unroll
        for (int hj = 0; hj < 8; hj++) {
          oacc[0][hj] = __builtin_amdgcn_mfma_f32_16x16x32_bf16(av[hj].v, pf0.v, oacc[0][hj], 0, 0, 0);
          oacc[1][hj] = __builtin_amdgcn_mfma_f32_16x16x32_bf16(av[hj].v, pf1.v, oacc[1][hj], 0, 0, 0);
        }
      }
    }
    __syncthreads();   // drains prefetch (issued a full compute ago) + buffer handoff
  }

  // epilogue: lane owns O^T[h][q=ti*16+c]; l is lane-local.
#pragma unroll
  for (int ti = 0; ti < 2; ti++) {
    float inv = 1.f / lrun[ti];
    int trow = t0 + w * 32 + ti * 16 + c;
#pragma unroll
    for (int hj = 0; hj < 8; hj++) {
      ushort4 o;
      o.x = f2bf(oacc[ti][hj][0] * inv);
      o.y = f2bf(oacc[ti][hj][1] * inv);
      o.z = f2bf(oacc[ti][hj][2] * inv);
      o.w = f2bf(oacc[ti][hj][3] * inv);
      *(ushort4*)&y[((size_t)(b * T_ + trow)) * HID_ + hq * HD_ + hj * 16 + grp * 4] = o;
    }
  }
}

// ---------------- launcher ----------------
extern "C" void kernel_launch(void* const* d_in, const int* in_sizes, int n_in,
                              void* d_out, int out_size, void* d_ws, size_t ws_size,
                              hipStream_t stream) {
  const float* x    = (const float*)d_in[0];
  const float* cosb = (const float*)d_in[1];
  const float* sinb = (const float*)d_in[2];
  const float* Wq   = (const float*)d_in[3];
  const float* Wk   = (const float*)d_in[4];
  const float* Wv   = (const float*)d_in[5];
  const float* Wo   = (const float*)d_in[6];
  float* out = (float*)d_out;

  char* ws = (char*)d_ws;
  size_t off = 0;
  auto take = [&](size_t elems) {
    unsigned short* p = (unsigned short*)(ws + off);
    off += ((elems * 2 + 255) & ~(size_t)255);
    return p;
  };
  unsigned short* xb   = take((size_t)M_ * HID_);
  unsigned short* wqkv = take((size_t)NQKV_ * HID_);
  unsigned short* wob  = take((size_t)HID_ * HID_);
  unsigned short* qkv  = take((size_t)M_ * NQKV_);
  unsigned short* qb   = take((size_t)B_ * NH_ * T_ * HD_);
  unsigned short* kb   = take((size_t)B_ * NKV_ * T_ * HD_);
  unsigned short* vb   = take((size_t)B_ * NKV_ * T_ * HD_);
  unsigned short* vtb  = take((size_t)B_ * NKV_ * T_ * HD_);
  unsigned short* yb   = take((size_t)M_ * HID_);
  (void)ws_size; (void)in_sizes; (void)n_in; (void)out_size;

  cast_bf16<<<16384, 256, 0, stream>>>(x, xb, 4194304);
  cast_w<<<5120, 256, 0, stream>>>(Wq, Wk, Wv, wqkv);
  cast_bf16<<<4096, 256, 0, stream>>>(Wo, wob, 1048576);

  gemm_bt<1><<<dim3(20, 64), 256, 0, stream>>>(xb, wqkv, qkv, M_, NQKV_, HID_);
  rope_norm<<<8192, 256, 0, stream>>>(qkv, cosb, sinb, qb, kb, vb);
  transpose_v<<<dim3(32, 2, 8), 256, 0, stream>>>(vb, vtb);
  flash_attn<<<dim3(1024), 256, 0, stream>>>(qb, kb, vtb, yb);
  gemm_bt<0><<<dim3(16, 64), 256, 0, stream>>>(yb, wob, out, M_, HID_, HID_);
}

// Round 2
// 528.005 us; speedup vs baseline: 1.4548x; 1.4548x over previous
//
#include <hip/hip_runtime.h>

// Problem constants (B,T,HID)=(4,2048,2048), heads 16, kv 2, hd 128.
#define B_    4
#define T_    2048
#define HID_  2048
#define NH_   16
#define NKV_  2
#define HD_   128
#define M_    (B_ * T_)      // 8192 rows
#define NQKV_ 2560           // 16*128 + 2*128 + 2*128

typedef __bf16 bf16x8 __attribute__((ext_vector_type(8)));
typedef float  f32x4  __attribute__((ext_vector_type(4)));

#define AS1 __attribute__((address_space(1)))
#define AS3 __attribute__((address_space(3)))

#if __has_builtin(__builtin_amdgcn_exp2f)
#define EXP2(x) __builtin_amdgcn_exp2f(x)
#else
#define EXP2(x) exp2f(x)
#endif

// async global->LDS, 16B per lane; LDS dest = wave-uniform base + lane*16
__device__ __forceinline__ void load_lds16(const void* g, void* l) {
  __builtin_amdgcn_global_load_lds((const AS1 unsigned int*)g,
                                   (AS3 unsigned int*)l, 16, 0, 0);
}

__device__ __forceinline__ unsigned short f2bf(float x) {
  union { float f; unsigned u; } a; a.f = x;
  unsigned r = a.u + 0x7fffu + ((a.u >> 16) & 1u);   // RNE
  return (unsigned short)(r >> 16);
}
__device__ __forceinline__ float bf2f(unsigned h) {
  union { unsigned u; float f; } a; a.u = h << 16;
  return a.f;
}
// pack two fp32 -> u32 of two bf16 (RTZ; P>=0, bias negligible)
__device__ __forceinline__ unsigned pk_rtz(float lo, float hi) {
  union { float f; unsigned u; } a, b; a.f = lo; b.f = hi;
  return (a.u >> 16) | (b.u & 0xffff0000u);
}

// ---------------- cast f32 -> bf16 (4 elems/thread) ----------------
__global__ __launch_bounds__(256) void cast_bf16(const float* __restrict__ in,
                                                 unsigned short* __restrict__ out,
                                                 int n4) {
  int i = blockIdx.x * 256 + threadIdx.x;
  if (i >= n4) return;
  float4 v = ((const float4*)in)[i];
  ushort4 o;
  o.x = f2bf(v.x); o.y = f2bf(v.y); o.z = f2bf(v.z); o.w = f2bf(v.w);
  ((ushort4*)out)[i] = o;
}

// merged Wq|Wk|Wv cast into contiguous wqkv (dest float4-index == i)
__global__ __launch_bounds__(256) void cast_w(const float* __restrict__ Wq,
                                              const float* __restrict__ Wk,
                                              const float* __restrict__ Wv,
                                              unsigned short* __restrict__ out) {
  int i = blockIdx.x * 256 + threadIdx.x;  // 5120*256 = 1310720 exact
  const float* src; int j;
  if (i < 1048576)      { src = Wq; j = i; }
  else if (i < 1179648) { src = Wk; j = i - 1048576; }
  else                  { src = Wv; j = i - 1179648; }
  float4 v = ((const float4*)src)[j];
  ushort4 o;
  o.x = f2bf(v.x); o.y = f2bf(v.y); o.z = f2bf(v.z); o.w = f2bf(v.w);
  ((ushort4*)out)[i] = o;
}

// ---------------- GEMM C = A * B^T (A: MxK row-major bf16, B: NxK row-major bf16)
// m97-style + 16B-unit XOR swizzle by (row>>1)&3 to kill fragment-read bank conflicts.
template <int OUT_BF16>
__global__ __launch_bounds__(256) void gemm_bt(const unsigned short* __restrict__ A,
                                               const unsigned short* __restrict__ Bm,
                                               void* __restrict__ C,
                                               int M, int N, int K) {
  __shared__ __align__(16) unsigned short As[128 * 32];
  __shared__ __align__(16) unsigned short Bs[128 * 32];
  const int tid = threadIdx.x;
  const int w = tid >> 6, lane = tid & 63;
  const int m0 = blockIdx.y << 7, n0 = blockIdx.x << 7;
  const int c = lane & 15, grp = lane >> 4;
  const int lr = lane >> 2;
  const int su = (((lane & 3) ^ ((lr >> 1) & 3)) << 3);   // staging source unit (swizzled)
  const int sw = (c >> 1) & 3;                            // read-side swizzle key
  const int wm = (w & 1) << 6, wn = (w >> 1) << 6;
  f32x4 acc[4][4] = {};
  for (int k0 = 0; k0 < K; k0 += 32) {
    __syncthreads();
    {
      int r0 = w << 4;
      load_lds16(A + (size_t)(m0 + r0 + lr) * K + k0 + su, &As[r0 * 32]);
      load_lds16(A + (size_t)(m0 + 64 + r0 + lr) * K + k0 + su, &As[(64 + r0) * 32]);
      load_lds16(Bm + (size_t)(n0 + r0 + lr) * K + k0 + su, &Bs[r0 * 32]);
      load_lds16(Bm + (size_t)(n0 + 64 + r0 + lr) * K + k0 + su, &Bs[(64 + r0) * 32]);
    }
    __syncthreads();
    bf16x8 af[4], bf[4];
#pragma unroll
    for (int i = 0; i < 4; i++)
      af[i] = *(const bf16x8*)&As[(wm + i * 16 + c) * 32 + ((grp ^ sw) << 3)];
#pragma unroll
    for (int j = 0; j < 4; j++)
      bf[j] = *(const bf16x8*)&Bs[(wn + j * 16 + c) * 32 + ((grp ^ sw) << 3)];
#pragma unroll
    for (int i = 0; i < 4; i++)
#pragma unroll
      for (int j = 0; j < 4; j++)
        acc[i][j] = __builtin_amdgcn_mfma_f32_16x16x32_bf16(af[i], bf[j], acc[i][j], 0, 0, 0);
  }
#pragma unroll
  for (int i = 0; i < 4; i++)
#pragma unroll
    for (int j = 0; j < 4; j++)
#pragma unroll
      for (int r = 0; r < 4; r++) {
        int row = m0 + wm + i * 16 + grp * 4 + r;
        int col = n0 + wn + j * 16 + c;
        float v = acc[i][j][r];
        if (OUT_BF16) ((unsigned short*)C)[(size_t)row * N + col] = f2bf(v);
        else          ((float*)C)[(size_t)row * N + col] = v;
      }
}

// ---------------- RoPE + RMSNorm. One wave per head per (b,t).
// q additionally pre-scaled by attn_scale*log2(e) so flash's softmax uses exp2 directly.
__global__ __launch_bounds__(256) void rope_norm(const unsigned short* __restrict__ qkv,
                                                 const float* __restrict__ cosb,
                                                 const float* __restrict__ sinb,
                                                 unsigned short* __restrict__ qo,
                                                 unsigned short* __restrict__ ko,
                                                 unsigned short* __restrict__ vo) {
  const int m = blockIdx.x;
  const int b = m >> 11, t = m & 2047;
  const int w = threadIdx.x >> 6, lane = threadIdx.x & 63;
  const float cv = cosb[t * 64 + lane], sv = sinb[t * 64 + lane];
  const unsigned short* row = qkv + (size_t)m * NQKV_;
  const float QSCL = 0.08838834764831845f * 1.4426950408889634f;  // 1/sqrt(128)*log2(e)
  for (int hh = w; hh < 20; hh += 4) {
    if (hh < 18) {
      const int col0 = (hh < 16) ? hh * 128 : 2048 + (hh - 16) * 128;
      unsigned pr = *(const unsigned*)(row + col0 + 2 * lane);
      float xr = bf2f(pr & 0xffffu), xi = bf2f(pr >> 16);
      float orr = xr * cv - xi * sv;
      float oi  = xr * sv + xi * cv;
      float ss = orr * orr + oi * oi;
#pragma unroll
      for (int off = 1; off < 64; off <<= 1) ss += __shfl_xor(ss, off);
      float scl = rsqrtf(ss * (1.0f / 128.0f) + 1.1920929e-07f);  // fp32 eps
      if (hh < 16) {
        float s2 = scl * QSCL;
        unsigned out = (unsigned)f2bf(orr * s2) | ((unsigned)f2bf(oi * s2) << 16);
        *(unsigned*)(qo + (((size_t)(b * NH_ + hh)) * T_ + t) * HD_ + 2 * lane) = out;
      } else {
        unsigned out = (unsigned)f2bf(orr * scl) | ((unsigned)f2bf(oi * scl) << 16);
        *(unsigned*)(ko + (((size_t)(b * NKV_ + (hh - 16))) * T_ + t) * HD_ + 2 * lane) = out;
      }
    } else {
      const int gg = hh - 18;
      unsigned pr = *(const unsigned*)(row + 2304 + gg * 128 + 2 * lane);
      *(unsigned*)(vo + (((size_t)(b * NKV_ + gg)) * T_ + t) * HD_ + 2 * lane) = pr;
    }
  }
}

// ---------------- V transpose: (bg, T, HD) -> (bg, HD, T), 64x64 LDS tiles.
// Output columns are PERMUTED within each 32-kv chunk so flash's PV A-fragment
// is one contiguous b128: position p=8g+4a+b holds kv=16a+4g+b.
__global__ __launch_bounds__(256) void transpose_v(const unsigned short* __restrict__ v,
                                                   unsigned short* __restrict__ vt) {
  __shared__ unsigned short tile[64][65];
  const int bg = blockIdx.z;
  const int t0 = blockIdx.x << 6, h0 = blockIdx.y << 6;
  const unsigned short* src = v + (size_t)bg * T_ * HD_;
  unsigned short* dst = vt + (size_t)bg * T_ * HD_;
  const int tid = threadIdx.x;
  const int rr = tid >> 4, cc = (tid & 15) << 2;
  const int u = (cc >> 2) & 7;
  const int cp = (cc & 32) + 16 * (u & 1) + 4 * ((u >> 1) & 3);  // source col for dst col cc
#pragma unroll
  for (int it = 0; it < 4; it++) {
    int r = rr + it * 16;
    ushort4 d = *(const ushort4*)(src + (size_t)(t0 + r) * HD_ + h0 + cc);
    tile[r][cc + 0] = d.x; tile[r][cc + 1] = d.y;
    tile[r][cc + 2] = d.z; tile[r][cc + 3] = d.w;
  }
  __syncthreads();
#pragma unroll
  for (int it = 0; it < 4; it++) {
    int r = rr + it * 16;
    ushort4 d;
    d.x = tile[cp + 0][r]; d.y = tile[cp + 1][r];
    d.z = tile[cp + 2][r]; d.w = tile[cp + 3][r];
    *(ushort4*)(dst + (size_t)(h0 + r) * T_ + t0 + cc) = d;
  }
}

// ---------------- Flash attention v5: round-0 structure (LDS-staged K AND V,
// single barrier per chunk, async global_load_lds prefetch) but with 32-kv
// chunks so LDS = 32 KiB/block (K 2x8KB + V 2x8KB) -> 4-5 blocks/CU instead
// of 2 (round-0's occupancy cap was the LDS, not VGPRs: 92 VGPR allows 5
// waves/SIMD). Balanced 1D grid: every mod-256 CU slot gets tiles
// {15-u, u, 15-((u+2)&15), (u+2)&15} = exactly 136 chunks of total work.
// Defer-max (T13, THR=8) kills the per-chunk oacc-rescale that would
// otherwise double in frequency with the smaller chunks.
__global__ __launch_bounds__(256, 2) void flash_attn(const unsigned short* __restrict__ q,
                                                     const unsigned short* __restrict__ k,
                                                     const unsigned short* __restrict__ vt,
                                                     unsigned short* __restrict__ y) {
  __shared__ __align__(16) unsigned short Kb[2][4096];  // [buf][dc4][kv32][unit swz] 8KB each
  __shared__ __align__(16) unsigned short Vb[2][4096];  // [buf][h128][kv-unit swz] 8KB each
  const int tid = threadIdx.x;
  const int w = tid >> 6, lane = tid & 63;
  const int c = lane & 15, grp = lane >> 4;
  const int lr = lane >> 2;
  const int sw = (c >> 1) & 3;
  const int su = (((lane & 3) ^ ((lr >> 1) & 3)) << 3);

  // balanced (tile, head, batch) decode from 1D block id
  const int idx = blockIdx.x;                 // 0..1023
  const int j = idx >> 8;                     // generation 0..3
  const int u = idx & 15;
  const int v = (idx >> 4) & 15;
  const int tp = (u + 2 * (j >> 1)) & 15;
  const int tile_i = (j & 1) ? tp : (15 - tp);  // heavy-first within each gen
  const int t0 = tile_i << 7;
  const int hq = v, b = j, g = hq >> 3;
  const int t0w = t0 + w * 32;

  const unsigned short* qbase = q + (((size_t)(b * NH_ + hq)) * T_ + t0) * HD_;
  const unsigned short* kbase = k + ((size_t)(b * NKV_ + g)) * T_ * HD_;
  const unsigned short* vtbase = vt + ((size_t)(b * NKV_ + g)) * HD_ * T_;

  // Q fragments (pre-scaled by scale*log2e): B-operand layout, rows q
  bf16x8 qf[2][4];
#pragma unroll
  for (int ti = 0; ti < 2; ti++)
#pragma unroll
    for (int ks = 0; ks < 4; ks++)
      qf[ti][ks] = *(const bf16x8*)(qbase + (size_t)(w * 32 + ti * 16 + c) * HD_ + ks * 32 + grp * 8);

  f32x4 oacc[2][8] = {};            // O^T: row h=hj*16+grp*4+r, col q=ti*16+c
  float mrun[2], lrun[2];
  mrun[0] = mrun[1] = -__builtin_inff();
  lrun[0] = lrun[1] = 0.f;

  // Stage one 32-kv chunk: wave w stages K d-chunk w (32 hd x 32 kv) and
  // V h-rows w*32..w*32+31. 4 load_lds16 per thread, all linear-dest.
  auto stage = [&](int s0, int bb) {
    const unsigned short* kp = kbase + (size_t)(s0 + lr) * HD_ + w * 32 + su;
    load_lds16(kp,                   &Kb[bb][w * 1024]);
    load_lds16(kp + (size_t)16 * HD_, &Kb[bb][w * 1024 + 512]);
    const unsigned short* vp = vtbase + s0 + su;
    load_lds16(vp + (size_t)(w * 32 + lr) * T_,      &Vb[bb][(w * 32) * 32]);
    load_lds16(vp + (size_t)(w * 32 + 16 + lr) * T_, &Vb[bb][(w * 32 + 16) * 32]);
  };

  const int nch = (t0 >> 5) + 4;
  stage(0, 0);
  __syncthreads();                       // chunk 0 resident
  for (int ic = 0; ic < nch; ic++) {
    const int s0 = ic << 5, bb = ic & 1;
    if (ic + 1 < nch) stage((ic + 1) << 5, bb ^ 1);   // async prefetch, drained at loop-end barrier
    if (s0 <= t0w + 31) {                // wave has unmasked work in this chunk
      const unsigned short* Kc = Kb[bb];
      const unsigned short* Vc = Vb[bb];
      // S^T = K·Q^T : lane holds P[q=ti*16+c][kv=kvt*16+grp*4+r] (log2 domain)
      f32x4 st[2][2] = {};
#pragma unroll
      for (int s = 0; s < 4; s++)
#pragma unroll
        for (int kvt = 0; kvt < 2; kvt++) {
          bf16x8 ak = *(const bf16x8*)&Kc[s * 1024 + (kvt * 16 + c) * 32 + ((grp ^ sw) << 3)];
          st[0][kvt] = __builtin_amdgcn_mfma_f32_16x16x32_bf16(ak, qf[0][s], st[0][kvt], 0, 0, 0);
          st[1][kvt] = __builtin_amdgcn_mfma_f32_16x16x32_bf16(ak, qf[1][s], st[1][kvt], 0, 0, 0);
        }
      if (s0 + 31 > t0w) {               // diagonal chunk: causal mask
#pragma unroll
        for (int ti = 0; ti < 2; ti++)
#pragma unroll
          for (int kvt = 0; kvt < 2; kvt++)
#pragma unroll
            for (int r = 0; r < 4; r++) {
              int kv = s0 + kvt * 16 + grp * 4 + r;
              int qq = t0w + ti * 16 + c;
              if (kv > qq) st[ti][kvt][r] = -__builtin_inff();
            }
      }
      // online softmax per q-column (lane-local + cross-grp butterfly)
      // defer-max: skip the oacc rescale unless some column's max grew >8
      // (log2 domain; P bounded by 2^8, fine in f32). Chunk 0 always takes
      // the rescale path (mrun=-inf), so mrun is finite thereafter -> the
      // -inf masked scores always give p = exp2(-inf - finite) = 0.
      unsigned pkv[2][2][2];
#pragma unroll
      for (int ti = 0; ti < 2; ti++) {
        float rm = fmaxf(fmaxf(st[ti][0][0], st[ti][0][1]), fmaxf(st[ti][0][2], st[ti][0][3]));
        rm = fmaxf(rm, fmaxf(fmaxf(st[ti][1][0], st[ti][1][1]), fmaxf(st[ti][1][2], st[ti][1][3])));
        rm = fmaxf(rm, __shfl_xor(rm, 16));
        rm = fmaxf(rm, __shfl_xor(rm, 32));
        if (!__all(rm <= mrun[ti] + 8.f)) {
          float mnew = fmaxf(mrun[ti], rm);
          float alpha = EXP2(mrun[ti] - mnew);
          mrun[ti] = mnew;
          lrun[ti] *= alpha;
#pragma unroll
          for (int hj = 0; hj < 8; hj++)
#pragma unroll
            for (int r = 0; r < 4; r++) oacc[ti][hj][r] *= alpha;
        }
        const float m0 = mrun[ti];
        float rs = 0.f;
#pragma unroll
        for (int kvt = 0; kvt < 2; kvt++) {
          float p0 = EXP2(st[ti][kvt][0] - m0);
          float p1 = EXP2(st[ti][kvt][1] - m0);
          float p2 = EXP2(st[ti][kvt][2] - m0);
          float p3 = EXP2(st[ti][kvt][3] - m0);
          rs += (p0 + p1) + (p2 + p3);
          pkv[ti][kvt][0] = pk_rtz(p0, p1);
          pkv[ti][kvt][1] = pk_rtz(p2, p3);
        }
        rs += __shfl_xor(rs, 16);
        rs += __shfl_xor(rs, 32);
        lrun[ti] += rs;
      }
      // O^T += V^T·P (kv permuted; V pre-permuted so A-frag is one b128)
      union { int4 i; bf16x8 v; } pf0, pf1;
      pf0.i = make_int4(pkv[0][0][0], pkv[0][0][1], pkv[0][1][0], pkv[0][1][1]);
      pf1.i = make_int4(pkv[1][0][0], pkv[1][0][1], pkv[1][1][0], pkv[1][1][1]);
#pragma unroll
      for (int hj = 0; hj < 8; hj++) {
        union { int4 i; bf16x8 v; } av;
        av.i = *(const int4*)&Vc[(hj * 16 + c) * 32 + ((grp ^ sw) << 3)];
        oacc[0][hj] = __builtin_amdgcn_mfma_f32_16x16x32_bf16(av.v, pf0.v, oacc[0][hj], 0, 0, 0);
        oacc[1][hj] = __builtin_amdgcn_mfma_f32_16x16x32_bf16(av.v, pf1.v, oacc[1][hj], 0, 0, 0);
      }
    }
    __syncthreads();   // drains prefetch (issued a full compute ago) + buffer handoff
  }

  // epilogue: lane owns O^T[h][q=ti*16+c]; l is lane-local.
#pragma unroll
  for (int ti = 0; ti < 2; ti++) {
    float inv = 1.f / lrun[ti];
    int trow = t0 + w * 32 + ti * 16 + c;
#pragma unroll
    for (int hj = 0; hj < 8; hj++) {
      ushort4 o;
      o.x = f2bf(oacc[ti][hj][0] * inv);
      o.y = f2bf(oacc[ti][hj][1] * inv);
      o.z = f2bf(oacc[ti][hj][2] * inv);
      o.w = f2bf(oacc[ti][hj][3] * inv);
      *(ushort4*)&y[((size_t)(b * T_ + trow)) * HID_ + hq * HD_ + hj * 16 + grp * 4] = o;
    }
  }
}

// ---------------- launcher ----------------
extern "C" void kernel_launch(void* const* d_in, const int* in_sizes, int n_in,
                              void* d_out, int out_size, void* d_ws, size_t ws_size,
                              hipStream_t stream) {
  const float* x    = (const float*)d_in[0];
  const float* cosb = (const float*)d_in[1];
  const float* sinb = (const float*)d_in[2];
  const float* Wq   = (const float*)d_in[3];
  const float* Wk   = (const float*)d_in[4];
  const float* Wv   = (const float*)d_in[5];
  const float* Wo   = (const float*)d_in[6];
  float* out = (float*)d_out;

  char* ws = (char*)d_ws;
  size_t off = 0;
  auto take = [&](size_t elems) {
    unsigned short* p = (unsigned short*)(ws + off);
    off += ((elems * 2 + 255) & ~(size_t)255);
    return p;
  };
  unsigned short* xb   = take((size_t)M_ * HID_);
  unsigned short* wqkv = take((size_t)NQKV_ * HID_);
  unsigned short* wob  = take((size_t)HID_ * HID_);
  unsigned short* qkv  = take((size_t)M_ * NQKV_);
  unsigned short* qb   = take((size_t)B_ * NH_ * T_ * HD_);
  unsigned short* kb   = take((size_t)B_ * NKV_ * T_ * HD_);
  unsigned short* vb   = take((size_t)B_ * NKV_ * T_ * HD_);
  unsigned short* vtb  = take((size_t)B_ * NKV_ * T_ * HD_);
  unsigned short* yb   = take((size_t)M_ * HID_);
  (void)ws_size; (void)in_sizes; (void)n_in; (void)out_size;

  cast_bf16<<<16384, 256, 0, stream>>>(x, xb, 4194304);
  cast_w<<<5120, 256, 0, stream>>>(Wq, Wk, Wv, wqkv);
  cast_bf16<<<4096, 256, 0, stream>>>(Wo, wob, 1048576);

  gemm_bt<1><<<dim3(20, 64), 256, 0, stream>>>(xb, wqkv, qkv, M_, NQKV_, HID_);
  rope_norm<<<8192, 256, 0, stream>>>(qkv, cosb, sinb, qb, kb, vb);
  transpose_v<<<dim3(32, 2, 8), 256, 0, stream>>>(vb, vtb);
  flash_attn<<<dim3(1024), 256, 0, stream>>>(qb, kb, vtb, yb);
  gemm_bt<0><<<dim3(16, 64), 256, 0, stream>>>(yb, wob, out, M_, HID_, HID_);
}

// Round 3
// 478.345 us; speedup vs baseline: 1.6058x; 1.1038x over previous
//
#include <hip/hip_runtime.h>

// Problem constants (B,T,HID)=(4,2048,2048), heads 16, kv 2, hd 128.
#define B_    4
#define T_    2048
#define HID_  2048
#define NH_   16
#define NKV_  2
#define HD_   128
#define M_    (B_ * T_)      // 8192 rows
#define NQKV_ 2560           // 16*128 + 2*128 + 2*128

typedef __bf16 bf16x8 __attribute__((ext_vector_type(8)));
typedef float  f32x4  __attribute__((ext_vector_type(4)));

#define AS1 __attribute__((address_space(1)))
#define AS3 __attribute__((address_space(3)))

#if __has_builtin(__builtin_amdgcn_exp2f)
#define EXP2(x) __builtin_amdgcn_exp2f(x)
#else
#define EXP2(x) exp2f(x)
#endif

// async global->LDS, 16B per lane; LDS dest = wave-uniform base + lane*16
__device__ __forceinline__ void load_lds16(const void* g, void* l) {
  __builtin_amdgcn_global_load_lds((const AS1 unsigned int*)g,
                                   (AS3 unsigned int*)l, 16, 0, 0);
}

__device__ __forceinline__ unsigned short f2bf(float x) {
  union { float f; unsigned u; } a; a.f = x;
  unsigned r = a.u + 0x7fffu + ((a.u >> 16) & 1u);   // RNE
  return (unsigned short)(r >> 16);
}
__device__ __forceinline__ float bf2f(unsigned h) {
  union { unsigned u; float f; } a; a.u = h << 16;
  return a.f;
}
// pack two fp32 -> u32 of two bf16 (RTZ; P>=0, bias negligible)
__device__ __forceinline__ unsigned pk_rtz(float lo, float hi) {
  union { float f; unsigned u; } a, b; a.f = lo; b.f = hi;
  return (a.u >> 16) | (b.u & 0xffff0000u);
}

// ---------------- cast f32 -> bf16 (4 elems/thread) ----------------
__global__ __launch_bounds__(256) void cast_bf16(const float* __restrict__ in,
                                                 unsigned short* __restrict__ out,
                                                 int n4) {
  int i = blockIdx.x * 256 + threadIdx.x;
  if (i >= n4) return;
  float4 v = ((const float4*)in)[i];
  ushort4 o;
  o.x = f2bf(v.x); o.y = f2bf(v.y); o.z = f2bf(v.z); o.w = f2bf(v.w);
  ((ushort4*)out)[i] = o;
}

// merged Wq|Wk|Wv cast into contiguous wqkv (dest float4-index == i)
__global__ __launch_bounds__(256) void cast_w(const float* __restrict__ Wq,
                                              const float* __restrict__ Wk,
                                              const float* __restrict__ Wv,
                                              unsigned short* __restrict__ out) {
  int i = blockIdx.x * 256 + threadIdx.x;  // 5120*256 = 1310720 exact
  const float* src; int j;
  if (i < 1048576)      { src = Wq; j = i; }
  else if (i < 1179648) { src = Wk; j = i - 1048576; }
  else                  { src = Wv; j = i - 1179648; }
  float4 v = ((const float4*)src)[j];
  ushort4 o;
  o.x = f2bf(v.x); o.y = f2bf(v.y); o.z = f2bf(v.z); o.w = f2bf(v.w);
  ((ushort4*)out)[i] = o;
}

// ---------------- GEMM C = A * B^T (A: MxK row-major bf16, B: NxK row-major bf16)
// m97-style + 16B-unit XOR swizzle by (row>>1)&3 to kill fragment-read bank conflicts.
template <int OUT_BF16>
__global__ __launch_bounds__(256) void gemm_bt(const unsigned short* __restrict__ A,
                                               const unsigned short* __restrict__ Bm,
                                               void* __restrict__ C,
                                               int M, int N, int K) {
  __shared__ __align__(16) unsigned short As[128 * 32];
  __shared__ __align__(16) unsigned short Bs[128 * 32];
  const int tid = threadIdx.x;
  const int w = tid >> 6, lane = tid & 63;
  const int m0 = blockIdx.y << 7, n0 = blockIdx.x << 7;
  const int c = lane & 15, grp = lane >> 4;
  const int lr = lane >> 2;
  const int su = (((lane & 3) ^ ((lr >> 1) & 3)) << 3);   // staging source unit (swizzled)
  const int sw = (c >> 1) & 3;                            // read-side swizzle key
  const int wm = (w & 1) << 6, wn = (w >> 1) << 6;
  f32x4 acc[4][4] = {};
  for (int k0 = 0; k0 < K; k0 += 32) {
    __syncthreads();
    {
      int r0 = w << 4;
      load_lds16(A + (size_t)(m0 + r0 + lr) * K + k0 + su, &As[r0 * 32]);
      load_lds16(A + (size_t)(m0 + 64 + r0 + lr) * K + k0 + su, &As[(64 + r0) * 32]);
      load_lds16(Bm + (size_t)(n0 + r0 + lr) * K + k0 + su, &Bs[r0 * 32]);
      load_lds16(Bm + (size_t)(n0 + 64 + r0 + lr) * K + k0 + su, &Bs[(64 + r0) * 32]);
    }
    __syncthreads();
    bf16x8 af[4], bf[4];
#pragma unroll
    for (int i = 0; i < 4; i++)
      af[i] = *(const bf16x8*)&As[(wm + i * 16 + c) * 32 + ((grp ^ sw) << 3)];
#pragma unroll
    for (int j = 0; j < 4; j++)
      bf[j] = *(const bf16x8*)&Bs[(wn + j * 16 + c) * 32 + ((grp ^ sw) << 3)];
#pragma unroll
    for (int i = 0; i < 4; i++)
#pragma unroll
      for (int j = 0; j < 4; j++)
        acc[i][j] = __builtin_amdgcn_mfma_f32_16x16x32_bf16(af[i], bf[j], acc[i][j], 0, 0, 0);
  }
#pragma unroll
  for (int i = 0; i < 4; i++)
#pragma unroll
    for (int j = 0; j < 4; j++)
#pragma unroll
      for (int r = 0; r < 4; r++) {
        int row = m0 + wm + i * 16 + grp * 4 + r;
        int col = n0 + wn + j * 16 + c;
        float v = acc[i][j][r];
        if (OUT_BF16) ((unsigned short*)C)[(size_t)row * N + col] = f2bf(v);
        else          ((float*)C)[(size_t)row * N + col] = v;
      }
}

// ---------------- RoPE + RMSNorm. One wave per head per (b,t).
// q additionally pre-scaled by attn_scale*log2(e) so flash's softmax uses exp2 directly.
__global__ __launch_bounds__(256) void rope_norm(const unsigned short* __restrict__ qkv,
                                                 const float* __restrict__ cosb,
                                                 const float* __restrict__ sinb,
                                                 unsigned short* __restrict__ qo,
                                                 unsigned short* __restrict__ ko,
                                                 unsigned short* __restrict__ vo) {
  const int m = blockIdx.x;
  const int b = m >> 11, t = m & 2047;
  const int w = threadIdx.x >> 6, lane = threadIdx.x & 63;
  const float cv = cosb[t * 64 + lane], sv = sinb[t * 64 + lane];
  const unsigned short* row = qkv + (size_t)m * NQKV_;
  const float QSCL = 0.08838834764831845f * 1.4426950408889634f;  // 1/sqrt(128)*log2(e)
  for (int hh = w; hh < 20; hh += 4) {
    if (hh < 18) {
      const int col0 = (hh < 16) ? hh * 128 : 2048 + (hh - 16) * 128;
      unsigned pr = *(const unsigned*)(row + col0 + 2 * lane);
      float xr = bf2f(pr & 0xffffu), xi = bf2f(pr >> 16);
      float orr = xr * cv - xi * sv;
      float oi  = xr * sv + xi * cv;
      float ss = orr * orr + oi * oi;
#pragma unroll
      for (int off = 1; off < 64; off <<= 1) ss += __shfl_xor(ss, off);
      float scl = rsqrtf(ss * (1.0f / 128.0f) + 1.1920929e-07f);  // fp32 eps
      if (hh < 16) {
        float s2 = scl * QSCL;
        unsigned out = (unsigned)f2bf(orr * s2) | ((unsigned)f2bf(oi * s2) << 16);
        *(unsigned*)(qo + (((size_t)(b * NH_ + hh)) * T_ + t) * HD_ + 2 * lane) = out;
      } else {
        unsigned out = (unsigned)f2bf(orr * scl) | ((unsigned)f2bf(oi * scl) << 16);
        *(unsigned*)(ko + (((size_t)(b * NKV_ + (hh - 16))) * T_ + t) * HD_ + 2 * lane) = out;
      }
    } else {
      const int gg = hh - 18;
      unsigned pr = *(const unsigned*)(row + 2304 + gg * 128 + 2 * lane);
      *(unsigned*)(vo + (((size_t)(b * NKV_ + gg)) * T_ + t) * HD_ + 2 * lane) = pr;
    }
  }
}

// ---------------- V transpose: (bg, T, HD) -> (bg, HD, T), 64x64 LDS tiles.
// Output columns are PERMUTED within each 32-kv chunk so flash's PV A-fragment
// is one contiguous b128: position p=8g+4a+b holds kv=16a+4g+b.
__global__ __launch_bounds__(256) void transpose_v(const unsigned short* __restrict__ v,
                                                   unsigned short* __restrict__ vt) {
  __shared__ unsigned short tile[64][65];
  const int bg = blockIdx.z;
  const int t0 = blockIdx.x << 6, h0 = blockIdx.y << 6;
  const unsigned short* src = v + (size_t)bg * T_ * HD_;
  unsigned short* dst = vt + (size_t)bg * T_ * HD_;
  const int tid = threadIdx.x;
  const int rr = tid >> 4, cc = (tid & 15) << 2;
  const int u = (cc >> 2) & 7;
  const int cp = (cc & 32) + 16 * (u & 1) + 4 * ((u >> 1) & 3);  // source col for dst col cc
#pragma unroll
  for (int it = 0; it < 4; it++) {
    int r = rr + it * 16;
    ushort4 d = *(const ushort4*)(src + (size_t)(t0 + r) * HD_ + h0 + cc);
    tile[r][cc + 0] = d.x; tile[r][cc + 1] = d.y;
    tile[r][cc + 2] = d.z; tile[r][cc + 3] = d.w;
  }
  __syncthreads();
#pragma unroll
  for (int it = 0; it < 4; it++) {
    int r = rr + it * 16;
    ushort4 d;
    d.x = tile[cp + 0][r]; d.y = tile[cp + 1][r];
    d.z = tile[cp + 2][r]; d.w = tile[cp + 3][r];
    *(ushort4*)(dst + (size_t)(h0 + r) * T_ + t0 + cc) = d;
  }
}

// ---------------- Flash attention v6: uniform-work paired blocks.
// Causal tile i costs 2i+2 64-kv chunks, so pair (i, 15-i) costs exactly 34
// chunks for EVERY pair. One block runs both tiles of a pair as two
// sequential phases (same (b,hq) -> same K/V stream; phase-1 chunks are
// L2-hot from phase 0). Grid = 512 uniform blocks = exactly the 2-block/CU
// LDS capacity (64 KiB each) -> every CU holds 2 identical-work blocks:
// constant 8 active waves/CU, zero finish skew, zero dispatch tail.
// (Round-2's 1024 mixed blocks were all co-resident; light ones finished in
// microseconds leaving CUs at 1 block for most of the run -> 19% time-avg occ.)
// Inner loop = round-0's proven 64-kv structure + round-2's defer-max +
// T5 setprio around MFMA clusters (m191: +4-7% attn at low occupancy).
__global__ __launch_bounds__(256, 2) void flash_attn(const unsigned short* __restrict__ q,
                                                     const unsigned short* __restrict__ k,
                                                     const unsigned short* __restrict__ vt,
                                                     unsigned short* __restrict__ y) {
  __shared__ __align__(16) unsigned short Kb[2][8192];  // [buf][dc4][kv64][d-unit swz]
  __shared__ __align__(16) unsigned short Vb[2][8192];  // [buf][ks2][h128][kv-unit swz]
  const int tid = threadIdx.x;
  const int w = tid >> 6, lane = tid & 63;
  const int c = lane & 15, grp = lane >> 4;
  const int lr = lane >> 2;
  const int sw = (c >> 1) & 3;
  const int su = (((lane & 3) ^ ((lr >> 1) & 3)) << 3);

  const int idx = blockIdx.x;            // 0..511
  const int p  = idx & 7;                // pair id: tiles {15-p, p}
  const int hq = (idx >> 3) & 15;
  const int b  = idx >> 7;
  const int g  = hq >> 3;

  const unsigned short* kbase  = k  + ((size_t)(b * NKV_ + g)) * T_ * HD_;
  const unsigned short* vtbase = vt + ((size_t)(b * NKV_ + g)) * HD_ * T_;

  auto stage = [&](int s0, int bb) {
    const unsigned short* kp = kbase + (size_t)(s0 + w * 16 + lr) * HD_ + su;
#pragma unroll
    for (int dc = 0; dc < 4; dc++)
      load_lds16(kp + dc * 32, &Kb[bb][dc * 2048 + (w * 16) * 32]);
    const unsigned short* vp = vtbase + s0 + su;
#pragma unroll
    for (int ks = 0; ks < 2; ks++)
#pragma unroll
      for (int jj = 0; jj < 2; jj++)
        load_lds16(vp + (size_t)(w * 32 + jj * 16 + lr) * T_ + ks * 32,
                   &Vb[bb][ks * 4096 + (w * 32 + jj * 16) * 32]);
  };

  for (int ph = 0; ph < 2; ph++) {
    const int tile = ph ? p : (15 - p);    // heavy phase first
    const int t0 = tile << 7;
    const int t0w = t0 + w * 32;
    const unsigned short* qbase = q + (((size_t)(b * NH_ + hq)) * T_ + t0) * HD_;

    // Q fragments (pre-scaled by scale*log2e): B-operand layout, rows q
    bf16x8 qf[2][4];
#pragma unroll
    for (int ti = 0; ti < 2; ti++)
#pragma unroll
      for (int ks = 0; ks < 4; ks++)
        qf[ti][ks] = *(const bf16x8*)(qbase + (size_t)(w * 32 + ti * 16 + c) * HD_ + ks * 32 + grp * 8);

    f32x4 oacc[2][8] = {};            // O^T: row h=hj*16+grp*4+r, col q=ti*16+c
    float mrun[2], lrun[2];
    mrun[0] = mrun[1] = -__builtin_inff();
    lrun[0] = lrun[1] = 0.f;

    const int nch = (t0 >> 6) + 2;
    stage(0, 0);                         // prior phase's final barrier guards the buffer
    __syncthreads();                     // chunk 0 resident
    for (int ic = 0; ic < nch; ic++) {
      const int s0 = ic << 6, bb = ic & 1;
      if (ic + 1 < nch) stage((ic + 1) << 6, bb ^ 1);  // async prefetch, drained at loop-end barrier
      if (s0 <= t0w + 31) {              // wave has unmasked work in this chunk
        const unsigned short* Kc = Kb[bb];
        const unsigned short* Vc = Vb[bb];
        // S^T = K·Q^T : lane holds P[q=ti*16+c][kv=kvt*16+grp*4+r] (log2 domain)
        f32x4 st[2][4] = {};
        __builtin_amdgcn_s_setprio(1);
#pragma unroll
        for (int s = 0; s < 4; s++)
#pragma unroll
          for (int kvt = 0; kvt < 4; kvt++) {
            bf16x8 ak = *(const bf16x8*)&Kc[s * 2048 + (kvt * 16 + c) * 32 + ((grp ^ sw) << 3)];
            st[0][kvt] = __builtin_amdgcn_mfma_f32_16x16x32_bf16(ak, qf[0][s], st[0][kvt], 0, 0, 0);
            st[1][kvt] = __builtin_amdgcn_mfma_f32_16x16x32_bf16(ak, qf[1][s], st[1][kvt], 0, 0, 0);
          }
        __builtin_amdgcn_s_setprio(0);
        if (s0 + 63 > t0w) {             // diagonal chunk: causal mask
#pragma unroll
          for (int ti = 0; ti < 2; ti++)
#pragma unroll
            for (int kvt = 0; kvt < 4; kvt++)
#pragma unroll
              for (int r = 0; r < 4; r++) {
                int kv = s0 + kvt * 16 + grp * 4 + r;
                int qq = t0w + ti * 16 + c;
                if (kv > qq) st[ti][kvt][r] = -__builtin_inff();
              }
        }
        // online softmax per q-column (lane-local + cross-grp butterfly).
        // defer-max (T13): skip the oacc rescale unless some column's max
        // grew >8 (log2 domain; P bounded by 2^8, fine in f32 accum).
        // Chunk 0 always rescales (mrun=-inf), so mrun is finite thereafter
        // and masked -inf scores give p = 0 exactly.
        unsigned pkv[2][4][2];
#pragma unroll
        for (int ti = 0; ti < 2; ti++) {
          float rm = st[ti][0][0];
#pragma unroll
          for (int kvt = 0; kvt < 4; kvt++)
#pragma unroll
            for (int r = 0; r < 4; r++) rm = fmaxf(rm, st[ti][kvt][r]);
          rm = fmaxf(rm, __shfl_xor(rm, 16));
          rm = fmaxf(rm, __shfl_xor(rm, 32));
          if (!__all(rm <= mrun[ti] + 8.f)) {
            float mnew = fmaxf(mrun[ti], rm);
            float alpha = EXP2(mrun[ti] - mnew);
            mrun[ti] = mnew;
            lrun[ti] *= alpha;
#pragma unroll
            for (int hj = 0; hj < 8; hj++)
#pragma unroll
              for (int r = 0; r < 4; r++) oacc[ti][hj][r] *= alpha;
          }
          const float m0 = mrun[ti];
          float rs = 0.f;
#pragma unroll
          for (int kvt = 0; kvt < 4; kvt++) {
            float p0 = EXP2(st[ti][kvt][0] - m0);
            float p1 = EXP2(st[ti][kvt][1] - m0);
            float p2 = EXP2(st[ti][kvt][2] - m0);
            float p3 = EXP2(st[ti][kvt][3] - m0);
            rs += (p0 + p1) + (p2 + p3);
            pkv[ti][kvt][0] = pk_rtz(p0, p1);
            pkv[ti][kvt][1] = pk_rtz(p2, p3);
          }
          rs += __shfl_xor(rs, 16);
          rs += __shfl_xor(rs, 32);
          lrun[ti] += rs;
        }
        // O^T += V^T·P (kv permuted; V pre-permuted so A-frag is one b128)
        __builtin_amdgcn_s_setprio(1);
#pragma unroll
        for (int s = 0; s < 2; s++) {
          union { int4 i; bf16x8 v; } pf0, pf1;
          pf0.i = make_int4(pkv[0][2 * s][0], pkv[0][2 * s][1], pkv[0][2 * s + 1][0], pkv[0][2 * s + 1][1]);
          pf1.i = make_int4(pkv[1][2 * s][0], pkv[1][2 * s][1], pkv[1][2 * s + 1][0], pkv[1][2 * s + 1][1]);
#pragma unroll
          for (int hj = 0; hj < 8; hj++) {
            union { int4 i; bf16x8 v; } av;
            av.i = *(const int4*)&Vc[s * 4096 + (hj * 16 + c) * 32 + ((grp ^ sw) << 3)];
            oacc[0][hj] = __builtin_amdgcn_mfma_f32_16x16x32_bf16(av.v, pf0.v, oacc[0][hj], 0, 0, 0);
            oacc[1][hj] = __builtin_amdgcn_mfma_f32_16x16x32_bf16(av.v, pf1.v, oacc[1][hj], 0, 0, 0);
          }
        }
        __builtin_amdgcn_s_setprio(0);
      }
      __syncthreads();   // drains prefetch (issued a full compute ago) + buffer handoff
    }

    // epilogue: lane owns O^T[h][q=ti*16+c]; l is lane-local.
#pragma unroll
    for (int ti = 0; ti < 2; ti++) {
      float inv = 1.f / lrun[ti];
      int trow = t0 + w * 32 + ti * 16 + c;
#pragma unroll
      for (int hj = 0; hj < 8; hj++) {
        ushort4 o;
        o.x = f2bf(oacc[ti][hj][0] * inv);
        o.y = f2bf(oacc[ti][hj][1] * inv);
        o.z = f2bf(oacc[ti][hj][2] * inv);
        o.w = f2bf(oacc[ti][hj][3] * inv);
        *(ushort4*)&y[((size_t)(b * T_ + trow)) * HID_ + hq * HD_ + hj * 16 + grp * 4] = o;
      }
    }
  }
}

// ---------------- launcher ----------------
extern "C" void kernel_launch(void* const* d_in, const int* in_sizes, int n_in,
                              void* d_out, int out_size, void* d_ws, size_t ws_size,
                              hipStream_t stream) {
  const float* x    = (const float*)d_in[0];
  const float* cosb = (const float*)d_in[1];
  const float* sinb = (const float*)d_in[2];
  const float* Wq   = (const float*)d_in[3];
  const float* Wk   = (const float*)d_in[4];
  const float* Wv   = (const float*)d_in[5];
  const float* Wo   = (const float*)d_in[6];
  float* out = (float*)d_out;

  char* ws = (char*)d_ws;
  size_t off = 0;
  auto take = [&](size_t elems) {
    unsigned short* p = (unsigned short*)(ws + off);
    off += ((elems * 2 + 255) & ~(size_t)255);
    return p;
  };
  unsigned short* xb   = take((size_t)M_ * HID_);
  unsigned short* wqkv = take((size_t)NQKV_ * HID_);
  unsigned short* wob  = take((size_t)HID_ * HID_);
  unsigned short* qkv  = take((size_t)M_ * NQKV_);
  unsigned short* qb   = take((size_t)B_ * NH_ * T_ * HD_);
  unsigned short* kb   = take((size_t)B_ * NKV_ * T_ * HD_);
  unsigned short* vb   = take((size_t)B_ * NKV_ * T_ * HD_);
  unsigned short* vtb  = take((size_t)B_ * NKV_ * T_ * HD_);
  unsigned short* yb   = take((size_t)M_ * HID_);
  (void)ws_size; (void)in_sizes; (void)n_in; (void)out_size;

  cast_bf16<<<16384, 256, 0, stream>>>(x, xb, 4194304);
  cast_w<<<5120, 256, 0, stream>>>(Wq, Wk, Wv, wqkv);
  cast_bf16<<<4096, 256, 0, stream>>>(Wo, wob, 1048576);

  gemm_bt<1><<<dim3(20, 64), 256, 0, stream>>>(xb, wqkv, qkv, M_, NQKV_, HID_);
  rope_norm<<<8192, 256, 0, stream>>>(qkv, cosb, sinb, qb, kb, vb);
  transpose_v<<<dim3(32, 2, 8), 256, 0, stream>>>(vb, vtb);
  flash_attn<<<dim3(512), 256, 0, stream>>>(qb, kb, vtb, yb);
  gemm_bt<0><<<dim3(16, 64), 256, 0, stream>>>(yb, wob, out, M_, HID_, HID_);
}

// Round 5
// 459.922 us; speedup vs baseline: 1.6701x; 1.0401x over previous
//
#include <hip/hip_runtime.h>

// Problem constants (B,T,HID)=(4,2048,2048), heads 16, kv 2, hd 128.
#define B_    4
#define T_    2048
#define HID_  2048
#define NH_   16
#define NKV_  2
#define HD_   128
#define M_    (B_ * T_)      // 8192 rows
#define NQKV_ 2560           // 16*128 + 2*128 + 2*128

typedef __bf16 bf16x8 __attribute__((ext_vector_type(8)));
typedef float  f32x4  __attribute__((ext_vector_type(4)));

#define AS1 __attribute__((address_space(1)))
#define AS3 __attribute__((address_space(3)))

#if __has_builtin(__builtin_amdgcn_exp2f)
#define EXP2(x) __builtin_amdgcn_exp2f(x)
#else
#define EXP2(x) exp2f(x)
#endif

// async global->LDS, 16B per lane; LDS dest = wave-uniform base + lane*16
__device__ __forceinline__ void load_lds16(const void* g, void* l) {
  __builtin_amdgcn_global_load_lds((const AS1 unsigned int*)g,
                                   (AS3 unsigned int*)l, 16, 0, 0);
}

__device__ __forceinline__ unsigned short f2bf(float x) {
  union { float f; unsigned u; } a; a.f = x;
  unsigned r = a.u + 0x7fffu + ((a.u >> 16) & 1u);   // RNE
  return (unsigned short)(r >> 16);
}
__device__ __forceinline__ float bf2f(unsigned h) {
  union { unsigned u; float f; } a; a.u = h << 16;
  return a.f;
}
// pack two fp32 -> u32 of two bf16 (RTZ; P>=0, bias negligible)
__device__ __forceinline__ unsigned pk_rtz(float lo, float hi) {
  union { float f; unsigned u; } a, b; a.f = lo; b.f = hi;
  return (a.u >> 16) | (b.u & 0xffff0000u);
}

// ---------------- cast f32 -> bf16 (4 elems/thread) ----------------
__global__ __launch_bounds__(256) void cast_bf16(const float* __restrict__ in,
                                                 unsigned short* __restrict__ out,
                                                 int n4) {
  int i = blockIdx.x * 256 + threadIdx.x;
  if (i >= n4) return;
  float4 v = ((const float4*)in)[i];
  ushort4 o;
  o.x = f2bf(v.x); o.y = f2bf(v.y); o.z = f2bf(v.z); o.w = f2bf(v.w);
  ((ushort4*)out)[i] = o;
}

// merged Wq|Wk|Wv cast into contiguous wqkv (dest float4-index == i)
__global__ __launch_bounds__(256) void cast_w(const float* __restrict__ Wq,
                                              const float* __restrict__ Wk,
                                              const float* __restrict__ Wv,
                                              unsigned short* __restrict__ out) {
  int i = blockIdx.x * 256 + threadIdx.x;  // 5120*256 = 1310720 exact
  const float* src; int j;
  if (i < 1048576)      { src = Wq; j = i; }
  else if (i < 1179648) { src = Wk; j = i - 1048576; }
  else                  { src = Wv; j = i - 1179648; }
  float4 v = ((const float4*)src)[j];
  ushort4 o;
  o.x = f2bf(v.x); o.y = f2bf(v.y); o.z = f2bf(v.z); o.w = f2bf(v.w);
  ((ushort4*)out)[i] = o;
}

// ---------------- GEMM v2: C = A * B^T, 256x256 tile, 8 waves (512 thr),
// BK=32 with FOUR LDS buffers (4 x (16KB A + 16KB B) = 128 KiB) and stage
// depth 3: while computing K-tile kt we stage kt+3 -> written buffer is never
// the read buffer (WAR-free by construction). Counted s_waitcnt vmcnt(8)
// once per K-tile (= 2 tiles in flight beyond kt+1), never 0 in the main
// loop; raw s_barrier (not __syncthreads) so the compiler's vmcnt(0) drain
// is gone (T3+T4: the counted vmcnt IS the 8-phase gain, m218).
// sched_barrier(0) after each counted wait pins LDS reads below it (rule #18).
// 2 phases per K-tile, 16 MFMA each, setprio(1) around the MFMA cluster (T5).
// Fragment layout + XOR swizzle identical to the proven 128^2 kernel.
#define GT_VM8  do { asm volatile("s_waitcnt vmcnt(8)" ::: "memory"); __builtin_amdgcn_sched_barrier(0); } while (0)
#define GT_VM4  do { asm volatile("s_waitcnt vmcnt(4)" ::: "memory"); __builtin_amdgcn_sched_barrier(0); } while (0)
#define GT_VM0  do { asm volatile("s_waitcnt vmcnt(0)" ::: "memory"); __builtin_amdgcn_sched_barrier(0); } while (0)
#define GT_NONE ((void)0)

#define GTILE(KT, DOSTAGE, VMW)                                               \
  {                                                                           \
    const int cb = (KT) & 3;                                                  \
    bf16x8 af[4];                                                             \
    _Pragma("unroll")                                                         \
    for (int nt = 0; nt < 4; nt++)                                            \
      bfr[nt] = *(const bf16x8*)&Bs[cb][(wc * 64 + nt * 16 + c) * 32 + rsw];  \
    _Pragma("unroll")                                                         \
    for (int mt = 0; mt < 4; mt++)                                            \
      af[mt] = *(const bf16x8*)&As[cb][(wr * 128 + mt * 16 + c) * 32 + rsw];  \
    if (DOSTAGE) {  /* stage A of KT+3 */                                     \
      const int sb = ((KT) + 3) & 3;                                          \
      const unsigned short* ap = A + a_stoff + (size_t)((KT) + 3) * 32;       \
      load_lds16(ap, &As[sb][(w * 16) * 32]);                                 \
      load_lds16(ap + (size_t)128 * K, &As[sb][(128 + w * 16) * 32]);         \
    }                                                                         \
    __builtin_amdgcn_s_barrier();                                             \
    __builtin_amdgcn_s_setprio(1);                                            \
    _Pragma("unroll")                                                         \
    for (int mt = 0; mt < 4; mt++)                                            \
      _Pragma("unroll")                                                       \
      for (int nt = 0; nt < 4; nt++)                                          \
        acc[mt][nt] = __builtin_amdgcn_mfma_f32_16x16x32_bf16(af[mt], bfr[nt], acc[mt][nt], 0, 0, 0); \
    __builtin_amdgcn_s_setprio(0);                                            \
    __builtin_amdgcn_s_barrier();                                             \
    _Pragma("unroll")                                                         \
    for (int mt = 0; mt < 4; mt++)                                            \
      af[mt] = *(const bf16x8*)&As[cb][(wr * 128 + 64 + mt * 16 + c) * 32 + rsw]; \
    if (DOSTAGE) {  /* stage B of KT+3 */                                     \
      const int sb = ((KT) + 3) & 3;                                          \
      const unsigned short* bp = Bm + b_stoff + (size_t)((KT) + 3) * 32;      \
      load_lds16(bp, &Bs[sb][(w * 16) * 32]);                                 \
      load_lds16(bp + (size_t)128 * K, &Bs[sb][(128 + w * 16) * 32]);         \
    }                                                                         \
    VMW;                                                                      \
    __builtin_amdgcn_s_barrier();                                             \
    __builtin_amdgcn_s_setprio(1);                                            \
    _Pragma("unroll")                                                         \
    for (int mt = 0; mt < 4; mt++)                                            \
      _Pragma("unroll")                                                       \
      for (int nt = 0; nt < 4; nt++)                                          \
        acc[4 + mt][nt] = __builtin_amdgcn_mfma_f32_16x16x32_bf16(af[mt], bfr[nt], acc[4 + mt][nt], 0, 0, 0); \
    __builtin_amdgcn_s_setprio(0);                                            \
    __builtin_amdgcn_s_barrier();                                             \
  }

template <int OUT_BF16>
__global__ __launch_bounds__(512, 2) void gemm_bt8(const unsigned short* __restrict__ A,
                                                   const unsigned short* __restrict__ Bm,
                                                   void* __restrict__ C,
                                                   int M, int N, int K) {
  __shared__ __align__(16) unsigned short As[4][256 * 32];  // 64 KiB
  __shared__ __align__(16) unsigned short Bs[4][256 * 32];  // 64 KiB
  const int tid = threadIdx.x;
  const int w = tid >> 6, lane = tid & 63;
  const int wr = w >> 2, wc = w & 3;                       // 2M x 4N wave grid
  const int c = lane & 15, grp = lane >> 4;
  const int lr = lane >> 2;
  const int su = (((lane & 3) ^ ((lr >> 1) & 3)) << 3);    // staging source unit (swizzled)
  const int rsw = ((grp ^ ((c >> 1) & 3)) << 3);           // read-side swizzled unit
  const int m0 = blockIdx.y << 8, n0 = blockIdx.x << 8;

  // loop-invariant per-thread staging offsets (rows w*16+lr and 128+w*16+lr)
  const size_t a_stoff = (size_t)(m0 + w * 16 + lr) * K + su;
  const size_t b_stoff = (size_t)(n0 + w * 16 + lr) * K + su;

  f32x4 acc[8][4] = {};
  bf16x8 bfr[4];
  const int nkt = K >> 5;   // 64 for K=2048

  // prologue: stage K-tiles 0,1,2 (12 loads/thread), drain to tile 0 resident
  {
#pragma unroll
    for (int kt = 0; kt < 3; kt++) {
      const unsigned short* ap = A + a_stoff + (size_t)kt * 32;
      load_lds16(ap, &As[kt][(w * 16) * 32]);
      load_lds16(ap + (size_t)128 * K, &As[kt][(128 + w * 16) * 32]);
      const unsigned short* bp = Bm + b_stoff + (size_t)kt * 32;
      load_lds16(bp, &Bs[kt][(w * 16) * 32]);
      load_lds16(bp + (size_t)128 * K, &Bs[kt][(128 + w * 16) * 32]);
    }
    GT_VM8;                        // oldest 4 (= tile 0's A+B) landed
    __builtin_amdgcn_s_barrier();
  }

  for (int kt = 0; kt + 3 < nkt; ++kt)
    GTILE(kt, 1, GT_VM8)           // stages kt+3; kt+1 guaranteed resident
  GTILE(nkt - 3, 0, GT_VM4)        // no more stages; nkt-2 resident
  GTILE(nkt - 2, 0, GT_VM0)        // nkt-1 resident
  GTILE(nkt - 1, 0, GT_NONE)

  // epilogue: acc[mt][nt] -> C rows m0+wr*128+(mt>>2)*64+(mt&3)*16+grp*4+r,
  //                         cols n0+wc*64+nt*16+c
#pragma unroll
  for (int mt = 0; mt < 8; mt++)
#pragma unroll
    for (int nt = 0; nt < 4; nt++)
#pragma unroll
      for (int r = 0; r < 4; r++) {
        int row = m0 + wr * 128 + (mt >> 2) * 64 + (mt & 3) * 16 + grp * 4 + r;
        int col = n0 + wc * 64 + nt * 16 + c;
        float v = acc[mt][nt][r];
        if (OUT_BF16) ((unsigned short*)C)[(size_t)row * N + col] = f2bf(v);
        else          ((float*)C)[(size_t)row * N + col] = v;
      }
}

// ---------------- RoPE + RMSNorm. One wave per head per (b,t).
// q additionally pre-scaled by attn_scale*log2(e) so flash's softmax uses exp2 directly.
__global__ __launch_bounds__(256) void rope_norm(const unsigned short* __restrict__ qkv,
                                                 const float* __restrict__ cosb,
                                                 const float* __restrict__ sinb,
                                                 unsigned short* __restrict__ qo,
                                                 unsigned short* __restrict__ ko,
                                                 unsigned short* __restrict__ vo) {
  const int m = blockIdx.x;
  const int b = m >> 11, t = m & 2047;
  const int w = threadIdx.x >> 6, lane = threadIdx.x & 63;
  const float cv = cosb[t * 64 + lane], sv = sinb[t * 64 + lane];
  const unsigned short* row = qkv + (size_t)m * NQKV_;
  const float QSCL = 0.08838834764831845f * 1.4426950408889634f;  // 1/sqrt(128)*log2(e)
  for (int hh = w; hh < 20; hh += 4) {
    if (hh < 18) {
      const int col0 = (hh < 16) ? hh * 128 : 2048 + (hh - 16) * 128;
      unsigned pr = *(const unsigned*)(row + col0 + 2 * lane);
      float xr = bf2f(pr & 0xffffu), xi = bf2f(pr >> 16);
      float orr = xr * cv - xi * sv;
      float oi  = xr * sv + xi * cv;
      float ss = orr * orr + oi * oi;
#pragma unroll
      for (int off = 1; off < 64; off <<= 1) ss += __shfl_xor(ss, off);
      float scl = rsqrtf(ss * (1.0f / 128.0f) + 1.1920929e-07f);  // fp32 eps
      if (hh < 16) {
        float s2 = scl * QSCL;
        unsigned out = (unsigned)f2bf(orr * s2) | ((unsigned)f2bf(oi * s2) << 16);
        *(unsigned*)(qo + (((size_t)(b * NH_ + hh)) * T_ + t) * HD_ + 2 * lane) = out;
      } else {
        unsigned out = (unsigned)f2bf(orr * scl) | ((unsigned)f2bf(oi * scl) << 16);
        *(unsigned*)(ko + (((size_t)(b * NKV_ + (hh - 16))) * T_ + t) * HD_ + 2 * lane) = out;
      }
    } else {
      const int gg = hh - 18;
      unsigned pr = *(const unsigned*)(row + 2304 + gg * 128 + 2 * lane);
      *(unsigned*)(vo + (((size_t)(b * NKV_ + gg)) * T_ + t) * HD_ + 2 * lane) = pr;
    }
  }
}

// ---------------- V transpose: (bg, T, HD) -> (bg, HD, T), 64x64 LDS tiles.
// Output columns are PERMUTED within each 32-kv chunk so flash's PV A-fragment
// is one contiguous b128: position p=8g+4a+b holds kv=16a+4g+b.
__global__ __launch_bounds__(256) void transpose_v(const unsigned short* __restrict__ v,
                                                   unsigned short* __restrict__ vt) {
  __shared__ unsigned short tile[64][65];
  const int bg = blockIdx.z;
  const int t0 = blockIdx.x << 6, h0 = blockIdx.y << 6;
  const unsigned short* src = v + (size_t)bg * T_ * HD_;
  unsigned short* dst = vt + (size_t)bg * T_ * HD_;
  const int tid = threadIdx.x;
  const int rr = tid >> 4, cc = (tid & 15) << 2;
  const int u = (cc >> 2) & 7;
  const int cp = (cc & 32) + 16 * (u & 1) + 4 * ((u >> 1) & 3);  // source col for dst col cc
#pragma unroll
  for (int it = 0; it < 4; it++) {
    int r = rr + it * 16;
    ushort4 d = *(const ushort4*)(src + (size_t)(t0 + r) * HD_ + h0 + cc);
    tile[r][cc + 0] = d.x; tile[r][cc + 1] = d.y;
    tile[r][cc + 2] = d.z; tile[r][cc + 3] = d.w;
  }
  __syncthreads();
#pragma unroll
  for (int it = 0; it < 4; it++) {
    int r = rr + it * 16;
    ushort4 d;
    d.x = tile[cp + 0][r]; d.y = tile[cp + 1][r];
    d.z = tile[cp + 2][r]; d.w = tile[cp + 3][r];
    *(ushort4*)(dst + (size_t)(h0 + r) * T_ + t0 + cc) = d;
  }
}

// ---------------- Flash attention v6: uniform-work paired blocks.
// Causal tile i costs 2i+2 64-kv chunks, so pair (i, 15-i) costs exactly 34
// chunks for EVERY pair. One block runs both tiles of a pair as two
// sequential phases (same (b,hq) -> same K/V stream; phase-1 chunks are
// L2-hot from phase 0). Grid = 512 uniform blocks = exactly the 2-block/CU
// LDS capacity (64 KiB each) -> every CU holds 2 identical-work blocks:
// constant 8 active waves/CU, zero finish skew, zero dispatch tail.
__global__ __launch_bounds__(256, 2) void flash_attn(const unsigned short* __restrict__ q,
                                                     const unsigned short* __restrict__ k,
                                                     const unsigned short* __restrict__ vt,
                                                     unsigned short* __restrict__ y) {
  __shared__ __align__(16) unsigned short Kb[2][8192];  // [buf][dc4][kv64][d-unit swz]
  __shared__ __align__(16) unsigned short Vb[2][8192];  // [buf][ks2][h128][kv-unit swz]
  const int tid = threadIdx.x;
  const int w = tid >> 6, lane = tid & 63;
  const int c = lane & 15, grp = lane >> 4;
  const int lr = lane >> 2;
  const int sw = (c >> 1) & 3;
  const int su = (((lane & 3) ^ ((lr >> 1) & 3)) << 3);

  const int idx = blockIdx.x;            // 0..511
  const int p  = idx & 7;                // pair id: tiles {15-p, p}
  const int hq = (idx >> 3) & 15;
  const int b  = idx >> 7;
  const int g  = hq >> 3;

  const unsigned short* kbase  = k  + ((size_t)(b * NKV_ + g)) * T_ * HD_;
  const unsigned short* vtbase = vt + ((size_t)(b * NKV_ + g)) * HD_ * T_;

  auto stage = [&](int s0, int bb) {
    const unsigned short* kp = kbase + (size_t)(s0 + w * 16 + lr) * HD_ + su;
#pragma unroll
    for (int dc = 0; dc < 4; dc++)
      load_lds16(kp + dc * 32, &Kb[bb][dc * 2048 + (w * 16) * 32]);
    const unsigned short* vp = vtbase + s0 + su;
#pragma unroll
    for (int ks = 0; ks < 2; ks++)
#pragma unroll
      for (int jj = 0; jj < 2; jj++)
        load_lds16(vp + (size_t)(w * 32 + jj * 16 + lr) * T_ + ks * 32,
                   &Vb[bb][ks * 4096 + (w * 32 + jj * 16) * 32]);
  };

  for (int ph = 0; ph < 2; ph++) {
    const int tile = ph ? p : (15 - p);    // heavy phase first
    const int t0 = tile << 7;
    const int t0w = t0 + w * 32;
    const unsigned short* qbase = q + (((size_t)(b * NH_ + hq)) * T_ + t0) * HD_;

    // Q fragments (pre-scaled by scale*log2e): B-operand layout, rows q
    bf16x8 qf[2][4];
#pragma unroll
    for (int ti = 0; ti < 2; ti++)
#pragma unroll
      for (int ks = 0; ks < 4; ks++)
        qf[ti][ks] = *(const bf16x8*)(qbase + (size_t)(w * 32 + ti * 16 + c) * HD_ + ks * 32 + grp * 8);

    f32x4 oacc[2][8] = {};            // O^T: row h=hj*16+grp*4+r, col q=ti*16+c
    float mrun[2], lrun[2];
    mrun[0] = mrun[1] = -__builtin_inff();
    lrun[0] = lrun[1] = 0.f;

    const int nch = (t0 >> 6) + 2;
    stage(0, 0);                         // prior phase's final barrier guards the buffer
    __syncthreads();                     // chunk 0 resident
    for (int ic = 0; ic < nch; ic++) {
      const int s0 = ic << 6, bb = ic & 1;
      if (ic + 1 < nch) stage((ic + 1) << 6, bb ^ 1);  // async prefetch, drained at loop-end barrier
      if (s0 <= t0w + 31) {              // wave has unmasked work in this chunk
        const unsigned short* Kc = Kb[bb];
        const unsigned short* Vc = Vb[bb];
        // S^T = K·Q^T : lane holds P[q=ti*16+c][kv=kvt*16+grp*4+r] (log2 domain)
        f32x4 st[2][4] = {};
        __builtin_amdgcn_s_setprio(1);
#pragma unroll
        for (int s = 0; s < 4; s++)
#pragma unroll
          for (int kvt = 0; kvt < 4; kvt++) {
            bf16x8 ak = *(const bf16x8*)&Kc[s * 2048 + (kvt * 16 + c) * 32 + ((grp ^ sw) << 3)];
            st[0][kvt] = __builtin_amdgcn_mfma_f32_16x16x32_bf16(ak, qf[0][s], st[0][kvt], 0, 0, 0);
            st[1][kvt] = __builtin_amdgcn_mfma_f32_16x16x32_bf16(ak, qf[1][s], st[1][kvt], 0, 0, 0);
          }
        __builtin_amdgcn_s_setprio(0);
        if (s0 + 63 > t0w) {             // diagonal chunk: causal mask
#pragma unroll
          for (int ti = 0; ti < 2; ti++)
#pragma unroll
            for (int kvt = 0; kvt < 4; kvt++)
#pragma unroll
              for (int r = 0; r < 4; r++) {
                int kv = s0 + kvt * 16 + grp * 4 + r;
                int qq = t0w + ti * 16 + c;
                if (kv > qq) st[ti][kvt][r] = -__builtin_inff();
              }
        }
        // online softmax per q-column (lane-local + cross-grp butterfly).
        // defer-max (T13): skip the oacc rescale unless some column's max
        // grew >8 (log2 domain; P bounded by 2^8, fine in f32 accum).
        unsigned pkv[2][4][2];
#pragma unroll
        for (int ti = 0; ti < 2; ti++) {
          float rm = st[ti][0][0];
#pragma unroll
          for (int kvt = 0; kvt < 4; kvt++)
#pragma unroll
            for (int r = 0; r < 4; r++) rm = fmaxf(rm, st[ti][kvt][r]);
          rm = fmaxf(rm, __shfl_xor(rm, 16));
          rm = fmaxf(rm, __shfl_xor(rm, 32));
          if (!__all(rm <= mrun[ti] + 8.f)) {
            float mnew = fmaxf(mrun[ti], rm);
            float alpha = EXP2(mrun[ti] - mnew);
            mrun[ti] = mnew;
            lrun[ti] *= alpha;
#pragma unroll
            for (int hj = 0; hj < 8; hj++)
#pragma unroll
              for (int r = 0; r < 4; r++) oacc[ti][hj][r] *= alpha;
          }
          const float m0 = mrun[ti];
          float rs = 0.f;
#pragma unroll
          for (int kvt = 0; kvt < 4; kvt++) {
            float p0 = EXP2(st[ti][kvt][0] - m0);
            float p1 = EXP2(st[ti][kvt][1] - m0);
            float p2 = EXP2(st[ti][kvt][2] - m0);
            float p3 = EXP2(st[ti][kvt][3] - m0);
            rs += (p0 + p1) + (p2 + p3);
            pkv[ti][kvt][0] = pk_rtz(p0, p1);
            pkv[ti][kvt][1] = pk_rtz(p2, p3);
          }
          rs += __shfl_xor(rs, 16);
          rs += __shfl_xor(rs, 32);
          lrun[ti] += rs;
        }
        // O^T += V^T·P (kv permuted; V pre-permuted so A-frag is one b128)
        __builtin_amdgcn_s_setprio(1);
#pragma unroll
        for (int s = 0; s < 2; s++) {
          union { int4 i; bf16x8 v; } pf0, pf1;
          pf0.i = make_int4(pkv[0][2 * s][0], pkv[0][2 * s][1], pkv[0][2 * s + 1][0], pkv[0][2 * s + 1][1]);
          pf1.i = make_int4(pkv[1][2 * s][0], pkv[1][2 * s][1], pkv[1][2 * s + 1][0], pkv[1][2 * s + 1][1]);
#pragma unroll
          for (int hj = 0; hj < 8; hj++) {
            union { int4 i; bf16x8 v; } av;
            av.i = *(const int4*)&Vc[s * 4096 + (hj * 16 + c) * 32 + ((grp ^ sw) << 3)];
            oacc[0][hj] = __builtin_amdgcn_mfma_f32_16x16x32_bf16(av.v, pf0.v, oacc[0][hj], 0, 0, 0);
            oacc[1][hj] = __builtin_amdgcn_mfma_f32_16x16x32_bf16(av.v, pf1.v, oacc[1][hj], 0, 0, 0);
          }
        }
        __builtin_amdgcn_s_setprio(0);
      }
      __syncthreads();   // drains prefetch (issued a full compute ago) + buffer handoff
    }

    // epilogue: lane owns O^T[h][q=ti*16+c]; l is lane-local.
#pragma unroll
    for (int ti = 0; ti < 2; ti++) {
      float inv = 1.f / lrun[ti];
      int trow = t0 + w * 32 + ti * 16 + c;
#pragma unroll
      for (int hj = 0; hj < 8; hj++) {
        ushort4 o;
        o.x = f2bf(oacc[ti][hj][0] * inv);
        o.y = f2bf(oacc[ti][hj][1] * inv);
        o.z = f2bf(oacc[ti][hj][2] * inv);
        o.w = f2bf(oacc[ti][hj][3] * inv);
        *(ushort4*)&y[((size_t)(b * T_ + trow)) * HID_ + hq * HD_ + hj * 16 + grp * 4] = o;
      }
    }
  }
}

// ---------------- launcher ----------------
extern "C" void kernel_launch(void* const* d_in, const int* in_sizes, int n_in,
                              void* d_out, int out_size, void* d_ws, size_t ws_size,
                              hipStream_t stream) {
  const float* x    = (const float*)d_in[0];
  const float* cosb = (const float*)d_in[1];
  const float* sinb = (const float*)d_in[2];
  const float* Wq   = (const float*)d_in[3];
  const float* Wk   = (const float*)d_in[4];
  const float* Wv   = (const float*)d_in[5];
  const float* Wo   = (const float*)d_in[6];
  float* out = (float*)d_out;

  char* ws = (char*)d_ws;
  size_t off = 0;
  auto take = [&](size_t elems) {
    unsigned short* p = (unsigned short*)(ws + off);
    off += ((elems * 2 + 255) & ~(size_t)255);
    return p;
  };
  unsigned short* xb   = take((size_t)M_ * HID_);
  unsigned short* wqkv = take((size_t)NQKV_ * HID_);
  unsigned short* wob  = take((size_t)HID_ * HID_);
  unsigned short* qkv  = take((size_t)M_ * NQKV_);
  unsigned short* qb   = take((size_t)B_ * NH_ * T_ * HD_);
  unsigned short* kb   = take((size_t)B_ * NKV_ * T_ * HD_);
  unsigned short* vb   = take((size_t)B_ * NKV_ * T_ * HD_);
  unsigned short* vtb  = take((size_t)B_ * NKV_ * T_ * HD_);
  unsigned short* yb   = take((size_t)M_ * HID_);
  (void)ws_size; (void)in_sizes; (void)n_in; (void)out_size;

  cast_bf16<<<16384, 256, 0, stream>>>(x, xb, 4194304);
  cast_w<<<5120, 256, 0, stream>>>(Wq, Wk, Wv, wqkv);
  cast_bf16<<<4096, 256, 0, stream>>>(Wo, wob, 1048576);

  gemm_bt8<1><<<dim3(10, 32), 512, 0, stream>>>(xb, wqkv, qkv, M_, NQKV_, HID_);
  rope_norm<<<8192, 256, 0, stream>>>(qkv, cosb, sinb, qb, kb, vb);
  transpose_v<<<dim3(32, 2, 8), 256, 0, stream>>>(vb, vtb);
  flash_attn<<<dim3(512), 256, 0, stream>>>(qb, kb, vtb, yb);
  gemm_bt8<0><<<dim3(8, 32), 512, 0, stream>>>(yb, wob, out, M_, HID_, HID_);
}

// Round 6
// 458.993 us; speedup vs baseline: 1.6735x; 1.0020x over previous
//
#include <hip/hip_runtime.h>

// Problem constants (B,T,HID)=(4,2048,2048), heads 16, kv 2, hd 128.
#define B_    4
#define T_    2048
#define HID_  2048
#define NH_   16
#define NKV_  2
#define HD_   128
#define M_    (B_ * T_)      // 8192 rows
#define NQKV_ 2560           // 16*128 + 2*128 + 2*128

typedef __bf16 bf16x8 __attribute__((ext_vector_type(8)));
typedef float  f32x4  __attribute__((ext_vector_type(4)));

#define AS1 __attribute__((address_space(1)))
#define AS3 __attribute__((address_space(3)))

#if __has_builtin(__builtin_amdgcn_exp2f)
#define EXP2(x) __builtin_amdgcn_exp2f(x)
#else
#define EXP2(x) exp2f(x)
#endif

// async global->LDS, 16B per lane; LDS dest = wave-uniform base + lane*16
__device__ __forceinline__ void load_lds16(const void* g, void* l) {
  __builtin_amdgcn_global_load_lds((const AS1 unsigned int*)g,
                                   (AS3 unsigned int*)l, 16, 0, 0);
}

__device__ __forceinline__ unsigned short f2bf(float x) {
  union { float f; unsigned u; } a; a.f = x;
  unsigned r = a.u + 0x7fffu + ((a.u >> 16) & 1u);   // RNE
  return (unsigned short)(r >> 16);
}
__device__ __forceinline__ float bf2f(unsigned h) {
  union { unsigned u; float f; } a; a.u = h << 16;
  return a.f;
}
// pack two fp32 -> u32 of two bf16 (RTZ; P>=0, bias negligible)
__device__ __forceinline__ unsigned pk_rtz(float lo, float hi) {
  union { float f; unsigned u; } a, b; a.f = lo; b.f = hi;
  return (a.u >> 16) | (b.u & 0xffff0000u);
}

// ---------------- cast f32 -> bf16 (4 elems/thread) ----------------
__global__ __launch_bounds__(256) void cast_bf16(const float* __restrict__ in,
                                                 unsigned short* __restrict__ out,
                                                 int n4) {
  int i = blockIdx.x * 256 + threadIdx.x;
  if (i >= n4) return;
  float4 v = ((const float4*)in)[i];
  ushort4 o;
  o.x = f2bf(v.x); o.y = f2bf(v.y); o.z = f2bf(v.z); o.w = f2bf(v.w);
  ((ushort4*)out)[i] = o;
}

// merged Wq|Wk|Wv cast into contiguous wqkv (dest float4-index == i)
__global__ __launch_bounds__(256) void cast_w(const float* __restrict__ Wq,
                                              const float* __restrict__ Wk,
                                              const float* __restrict__ Wv,
                                              unsigned short* __restrict__ out) {
  int i = blockIdx.x * 256 + threadIdx.x;  // 5120*256 = 1310720 exact
  const float* src; int j;
  if (i < 1048576)      { src = Wq; j = i; }
  else if (i < 1179648) { src = Wk; j = i - 1048576; }
  else                  { src = Wv; j = i - 1179648; }
  float4 v = ((const float4*)src)[j];
  ushort4 o;
  o.x = f2bf(v.x); o.y = f2bf(v.y); o.z = f2bf(v.z); o.w = f2bf(v.w);
  ((ushort4*)out)[i] = o;
}

// ---------------- GEMM v3: 256x256 tile, BK=64, 8 waves (512 thr), true
// 4-phase-per-K-tile interleave (T3+T4+T5). LDS = 2 dbuf x (A 32KB + B 32KB)
// = 128 KiB. Per phase: {ds_read quad for a LATER MFMA cluster || issue ONE
// half-tile stage -> s_barrier -> setprio(1) -> 16 MFMA -> setprio(0) ->
// s_barrier}. vmcnt(6) once per K-tile (3 half-tiles in flight), never 0 in
// steady state (m218: counted vmcnt IS the gain; m196: coarse split is not).
// Stage slots: A1(kt+1)@ph1, B0(kt+2)@ph2, B1(kt+2)@ph3, A0(kt+2)@ph4.
// WAR-free: each half staged >=1 barrier-pair after its prior tenant's last
// read retires (B last read ph1; A-half read through ph3 -> staged ph4/ph1).
// Residency: at ph4's vmcnt(6), in-flight = kt+2's {B0,B1,A0} only.
// LDS swizzle: 128B rows, 8x16B units, phys_unit = logical ^ (row&7);
// source pre-swizzled (su), read XORs with c&7 -> 8 lanes/unit uniform.
template <int OUT_BF16>
__global__ __launch_bounds__(512, 1) void gemm256(const unsigned short* __restrict__ A,
                                                  const unsigned short* __restrict__ Bm,
                                                  void* __restrict__ C,
                                                  int M, int N, int K) {
  __shared__ __align__(16) unsigned short As[2][16384];  // [db][half*8192 + row*64 + u*8]
  __shared__ __align__(16) unsigned short Bs[2][16384];
  const int tid = threadIdx.x;
  const int w = tid >> 6, lane = tid & 63;
  const int wr = w >> 2, wc = w & 3;                 // 2M x 4N wave grid
  const int c = lane & 15, grp = lane >> 4;
  const int c7 = c & 7;
  const int m0 = blockIdx.y << 8, n0 = blockIdx.x << 8;
  const int srow = w * 8 + (lane >> 3);              // staging row within 64-row group
  const int su = ((lane & 7) ^ ((lane >> 3) & 7)) << 3;  // pre-swizzled source unit

  f32x4 acc[8][4] = {};
  const int nkt = K >> 6;                            // 32 for K=2048

  auto stA = [&](int h, int kt, int db) {
    const unsigned short* p = A + (size_t)(m0 + h * 128 + srow) * K + kt * 64 + su;
    load_lds16(p, &As[db][h * 8192 + (w * 8) * 64]);
    load_lds16(p + (size_t)64 * K, &As[db][h * 8192 + (64 + w * 8) * 64]);
  };
  auto stB = [&](int h, int kt, int db) {
    const unsigned short* p = Bm + (size_t)(n0 + h * 128 + srow) * K + kt * 64 + su;
    load_lds16(p, &Bs[db][h * 8192 + (w * 8) * 64]);
    load_lds16(p + (size_t)64 * K, &Bs[db][h * 8192 + (64 + w * 8) * 64]);
  };

  // prologue: kt0 fully + kt1 {B0,B1,A0}; vmcnt(6) -> kt0 resident
  stA(0, 0, 0); stA(1, 0, 0); stB(0, 0, 0); stB(1, 0, 0);
  if (nkt > 1) { stB(0, 1, 1); stB(1, 1, 1); stA(0, 1, 1); }
  asm volatile("s_waitcnt vmcnt(6)" ::: "memory");
  __builtin_amdgcn_s_barrier();

  const int Abase = wr * 8192;
  const int Bbase = (wc >> 1) * 8192 + ((wc & 1) * 64) * 64;

#define RDQ(arr, mtA, mtB)                                                          \
  _Pragma("unroll")                                                                 \
  for (int ks = 0; ks < 2; ks++) {                                                  \
    arr[0][ks] = *(const bf16x8*)&Ad[((mtA) * 16 + c) * 64 + (((ks << 2) + grp) ^ c7) * 8]; \
    arr[1][ks] = *(const bf16x8*)&Ad[((mtB) * 16 + c) * 64 + (((ks << 2) + grp) ^ c7) * 8]; \
  }
#define MMQ(arr, mt0)                                                               \
  __builtin_amdgcn_s_setprio(1);                                                    \
  _Pragma("unroll")                                                                 \
  for (int i = 0; i < 2; i++)                                                       \
    _Pragma("unroll")                                                               \
    for (int nt = 0; nt < 4; nt++)                                                  \
      _Pragma("unroll")                                                             \
      for (int ks = 0; ks < 2; ks++)                                                \
        acc[(mt0) + i][nt] = __builtin_amdgcn_mfma_f32_16x16x32_bf16(               \
            arr[i][ks], b_[nt][ks], acc[(mt0) + i][nt], 0, 0, 0);                   \
  __builtin_amdgcn_s_setprio(0);

  for (int kt = 0; kt < nkt; ++kt) {
    const int db = kt & 1;
    const unsigned short* Ad = &As[db][Abase];
    const unsigned short* Bd = &Bs[db][Bbase];
    bf16x8 b_[4][2], a01[2][2], a23[2][2], a45[2][2], a67[2][2];
    // ---- phase 1: read q0, B(8), q1; stage A1(kt+1); MFMA q0
    RDQ(a01, 0, 1)
#pragma unroll
    for (int nt = 0; nt < 4; nt++)
#pragma unroll
      for (int ks = 0; ks < 2; ks++)
        b_[nt][ks] = *(const bf16x8*)&Bd[(nt * 16 + c) * 64 + (((ks << 2) + grp) ^ c7) * 8];
    RDQ(a23, 2, 3)
    if (kt + 1 < nkt) stA(1, kt + 1, db ^ 1);
    __builtin_amdgcn_s_barrier();
    MMQ(a01, 0)
    __builtin_amdgcn_s_barrier();
    // ---- phase 2: read q2; stage B0(kt+2); MFMA q1
    RDQ(a45, 4, 5)
    if (kt + 2 < nkt) stB(0, kt + 2, db);
    __builtin_amdgcn_s_barrier();
    MMQ(a23, 2)
    __builtin_amdgcn_s_barrier();
    // ---- phase 3: read q3; stage B1(kt+2); MFMA q2
    RDQ(a67, 6, 7)
    if (kt + 2 < nkt) stB(1, kt + 2, db);
    __builtin_amdgcn_s_barrier();
    MMQ(a45, 4)
    __builtin_amdgcn_s_barrier();
    // ---- phase 4: stage A0(kt+2); counted vmcnt; MFMA q3
    if (kt + 2 < nkt) {
      stA(0, kt + 2, db);
      asm volatile("s_waitcnt vmcnt(6)" ::: "memory");
    } else {
      asm volatile("s_waitcnt vmcnt(0)" ::: "memory");
    }
    __builtin_amdgcn_s_barrier();
    MMQ(a67, 6)
    __builtin_amdgcn_s_barrier();
  }
#undef RDQ
#undef MMQ

  // epilogue: acc[mt][nt] -> row m0+wr*128+mt*16+grp*4+r, col n0+wc*64+nt*16+c
#pragma unroll
  for (int mt = 0; mt < 8; mt++)
#pragma unroll
    for (int nt = 0; nt < 4; nt++)
#pragma unroll
      for (int r = 0; r < 4; r++) {
        int row = m0 + wr * 128 + mt * 16 + grp * 4 + r;
        int col = n0 + wc * 64 + nt * 16 + c;
        float v = acc[mt][nt][r];
        if (OUT_BF16) ((unsigned short*)C)[(size_t)row * N + col] = f2bf(v);
        else          ((float*)C)[(size_t)row * N + col] = v;
      }
}

// ---------------- RoPE + RMSNorm. One wave per head per (b,t).
// q additionally pre-scaled by attn_scale*log2(e) so flash's softmax uses exp2 directly.
__global__ __launch_bounds__(256) void rope_norm(const unsigned short* __restrict__ qkv,
                                                 const float* __restrict__ cosb,
                                                 const float* __restrict__ sinb,
                                                 unsigned short* __restrict__ qo,
                                                 unsigned short* __restrict__ ko,
                                                 unsigned short* __restrict__ vo) {
  const int m = blockIdx.x;
  const int b = m >> 11, t = m & 2047;
  const int w = threadIdx.x >> 6, lane = threadIdx.x & 63;
  const float cv = cosb[t * 64 + lane], sv = sinb[t * 64 + lane];
  const unsigned short* row = qkv + (size_t)m * NQKV_;
  const float QSCL = 0.08838834764831845f * 1.4426950408889634f;  // 1/sqrt(128)*log2(e)
  for (int hh = w; hh < 20; hh += 4) {
    if (hh < 18) {
      const int col0 = (hh < 16) ? hh * 128 : 2048 + (hh - 16) * 128;
      unsigned pr = *(const unsigned*)(row + col0 + 2 * lane);
      float xr = bf2f(pr & 0xffffu), xi = bf2f(pr >> 16);
      float orr = xr * cv - xi * sv;
      float oi  = xr * sv + xi * cv;
      float ss = orr * orr + oi * oi;
#pragma unroll
      for (int off = 1; off < 64; off <<= 1) ss += __shfl_xor(ss, off);
      float scl = rsqrtf(ss * (1.0f / 128.0f) + 1.1920929e-07f);  // fp32 eps
      if (hh < 16) {
        float s2 = scl * QSCL;
        unsigned out = (unsigned)f2bf(orr * s2) | ((unsigned)f2bf(oi * s2) << 16);
        *(unsigned*)(qo + (((size_t)(b * NH_ + hh)) * T_ + t) * HD_ + 2 * lane) = out;
      } else {
        unsigned out = (unsigned)f2bf(orr * scl) | ((unsigned)f2bf(oi * scl) << 16);
        *(unsigned*)(ko + (((size_t)(b * NKV_ + (hh - 16))) * T_ + t) * HD_ + 2 * lane) = out;
      }
    } else {
      const int gg = hh - 18;
      unsigned pr = *(const unsigned*)(row + 2304 + gg * 128 + 2 * lane);
      *(unsigned*)(vo + (((size_t)(b * NKV_ + gg)) * T_ + t) * HD_ + 2 * lane) = pr;
    }
  }
}

// ---------------- V transpose: (bg, T, HD) -> (bg, HD, T), 64x64 LDS tiles.
// Output columns are PERMUTED within each 32-kv chunk so flash's PV A-fragment
// is one contiguous b128: position p=8g+4a+b holds kv=16a+4g+b.
__global__ __launch_bounds__(256) void transpose_v(const unsigned short* __restrict__ v,
                                                   unsigned short* __restrict__ vt) {
  __shared__ unsigned short tile[64][65];
  const int bg = blockIdx.z;
  const int t0 = blockIdx.x << 6, h0 = blockIdx.y << 6;
  const unsigned short* src = v + (size_t)bg * T_ * HD_;
  unsigned short* dst = vt + (size_t)bg * T_ * HD_;
  const int tid = threadIdx.x;
  const int rr = tid >> 4, cc = (tid & 15) << 2;
  const int u = (cc >> 2) & 7;
  const int cp = (cc & 32) + 16 * (u & 1) + 4 * ((u >> 1) & 3);  // source col for dst col cc
#pragma unroll
  for (int it = 0; it < 4; it++) {
    int r = rr + it * 16;
    ushort4 d = *(const ushort4*)(src + (size_t)(t0 + r) * HD_ + h0 + cc);
    tile[r][cc + 0] = d.x; tile[r][cc + 1] = d.y;
    tile[r][cc + 2] = d.z; tile[r][cc + 3] = d.w;
  }
  __syncthreads();
#pragma unroll
  for (int it = 0; it < 4; it++) {
    int r = rr + it * 16;
    ushort4 d;
    d.x = tile[cp + 0][r]; d.y = tile[cp + 1][r];
    d.z = tile[cp + 2][r]; d.w = tile[cp + 3][r];
    *(ushort4*)(dst + (size_t)(h0 + r) * T_ + t0 + cc) = d;
  }
}

// ---------------- Flash attention v6: uniform-work paired blocks.
// Causal tile i costs 2i+2 64-kv chunks, so pair (i, 15-i) costs exactly 34
// chunks for EVERY pair. One block runs both tiles of a pair as two
// sequential phases (same (b,hq) -> same K/V stream; phase-1 chunks are
// L2-hot from phase 0). Grid = 512 uniform blocks = exactly the 2-block/CU
// LDS capacity (64 KiB each) -> every CU holds 2 identical-work blocks:
// constant 8 active waves/CU, zero finish skew, zero dispatch tail.
__global__ __launch_bounds__(256, 2) void flash_attn(const unsigned short* __restrict__ q,
                                                     const unsigned short* __restrict__ k,
                                                     const unsigned short* __restrict__ vt,
                                                     unsigned short* __restrict__ y) {
  __shared__ __align__(16) unsigned short Kb[2][8192];  // [buf][dc4][kv64][d-unit swz]
  __shared__ __align__(16) unsigned short Vb[2][8192];  // [buf][ks2][h128][kv-unit swz]
  const int tid = threadIdx.x;
  const int w = tid >> 6, lane = tid & 63;
  const int c = lane & 15, grp = lane >> 4;
  const int lr = lane >> 2;
  const int sw = (c >> 1) & 3;
  const int su = (((lane & 3) ^ ((lr >> 1) & 3)) << 3);

  const int idx = blockIdx.x;            // 0..511
  const int p  = idx & 7;                // pair id: tiles {15-p, p}
  const int hq = (idx >> 3) & 15;
  const int b  = idx >> 7;
  const int g  = hq >> 3;

  const unsigned short* kbase  = k  + ((size_t)(b * NKV_ + g)) * T_ * HD_;
  const unsigned short* vtbase = vt + ((size_t)(b * NKV_ + g)) * HD_ * T_;

  auto stage = [&](int s0, int bb) {
    const unsigned short* kp = kbase + (size_t)(s0 + w * 16 + lr) * HD_ + su;
#pragma unroll
    for (int dc = 0; dc < 4; dc++)
      load_lds16(kp + dc * 32, &Kb[bb][dc * 2048 + (w * 16) * 32]);
    const unsigned short* vp = vtbase + s0 + su;
#pragma unroll
    for (int ks = 0; ks < 2; ks++)
#pragma unroll
      for (int jj = 0; jj < 2; jj++)
        load_lds16(vp + (size_t)(w * 32 + jj * 16 + lr) * T_ + ks * 32,
                   &Vb[bb][ks * 4096 + (w * 32 + jj * 16) * 32]);
  };

  for (int ph = 0; ph < 2; ph++) {
    const int tile = ph ? p : (15 - p);    // heavy phase first
    const int t0 = tile << 7;
    const int t0w = t0 + w * 32;
    const unsigned short* qbase = q + (((size_t)(b * NH_ + hq)) * T_ + t0) * HD_;

    // Q fragments (pre-scaled by scale*log2e): B-operand layout, rows q
    bf16x8 qf[2][4];
#pragma unroll
    for (int ti = 0; ti < 2; ti++)
#pragma unroll
      for (int ks = 0; ks < 4; ks++)
        qf[ti][ks] = *(const bf16x8*)(qbase + (size_t)(w * 32 + ti * 16 + c) * HD_ + ks * 32 + grp * 8);

    f32x4 oacc[2][8] = {};            // O^T: row h=hj*16+grp*4+r, col q=ti*16+c
    float mrun[2], lrun[2];
    mrun[0] = mrun[1] = -__builtin_inff();
    lrun[0] = lrun[1] = 0.f;

    const int nch = (t0 >> 6) + 2;
    stage(0, 0);                         // prior phase's final barrier guards the buffer
    __syncthreads();                     // chunk 0 resident
    for (int ic = 0; ic < nch; ic++) {
      const int s0 = ic << 6, bb = ic & 1;
      if (ic + 1 < nch) stage((ic + 1) << 6, bb ^ 1);  // async prefetch, drained at loop-end barrier
      if (s0 <= t0w + 31) {              // wave has unmasked work in this chunk
        const unsigned short* Kc = Kb[bb];
        const unsigned short* Vc = Vb[bb];
        // S^T = K·Q^T : lane holds P[q=ti*16+c][kv=kvt*16+grp*4+r] (log2 domain)
        f32x4 st[2][4] = {};
        __builtin_amdgcn_s_setprio(1);
#pragma unroll
        for (int s = 0; s < 4; s++)
#pragma unroll
          for (int kvt = 0; kvt < 4; kvt++) {
            bf16x8 ak = *(const bf16x8*)&Kc[s * 2048 + (kvt * 16 + c) * 32 + ((grp ^ sw) << 3)];
            st[0][kvt] = __builtin_amdgcn_mfma_f32_16x16x32_bf16(ak, qf[0][s], st[0][kvt], 0, 0, 0);
            st[1][kvt] = __builtin_amdgcn_mfma_f32_16x16x32_bf16(ak, qf[1][s], st[1][kvt], 0, 0, 0);
          }
        __builtin_amdgcn_s_setprio(0);
        if (s0 + 63 > t0w) {             // diagonal chunk: causal mask
#pragma unroll
          for (int ti = 0; ti < 2; ti++)
#pragma unroll
            for (int kvt = 0; kvt < 4; kvt++)
#pragma unroll
              for (int r = 0; r < 4; r++) {
                int kv = s0 + kvt * 16 + grp * 4 + r;
                int qq = t0w + ti * 16 + c;
                if (kv > qq) st[ti][kvt][r] = -__builtin_inff();
              }
        }
        // online softmax per q-column (lane-local + cross-grp butterfly).
        // defer-max (T13): skip the oacc rescale unless some column's max
        // grew >8 (log2 domain; P bounded by 2^8, fine in f32 accum).
        unsigned pkv[2][4][2];
#pragma unroll
        for (int ti = 0; ti < 2; ti++) {
          float rm = st[ti][0][0];
#pragma unroll
          for (int kvt = 0; kvt < 4; kvt++)
#pragma unroll
            for (int r = 0; r < 4; r++) rm = fmaxf(rm, st[ti][kvt][r]);
          rm = fmaxf(rm, __shfl_xor(rm, 16));
          rm = fmaxf(rm, __shfl_xor(rm, 32));
          if (!__all(rm <= mrun[ti] + 8.f)) {
            float mnew = fmaxf(mrun[ti], rm);
            float alpha = EXP2(mrun[ti] - mnew);
            mrun[ti] = mnew;
            lrun[ti] *= alpha;
#pragma unroll
            for (int hj = 0; hj < 8; hj++)
#pragma unroll
              for (int r = 0; r < 4; r++) oacc[ti][hj][r] *= alpha;
          }
          const float m0 = mrun[ti];
          float rs = 0.f;
#pragma unroll
          for (int kvt = 0; kvt < 4; kvt++) {
            float p0 = EXP2(st[ti][kvt][0] - m0);
            float p1 = EXP2(st[ti][kvt][1] - m0);
            float p2 = EXP2(st[ti][kvt][2] - m0);
            float p3 = EXP2(st[ti][kvt][3] - m0);
            rs += (p0 + p1) + (p2 + p3);
            pkv[ti][kvt][0] = pk_rtz(p0, p1);
            pkv[ti][kvt][1] = pk_rtz(p2, p3);
          }
          rs += __shfl_xor(rs, 16);
          rs += __shfl_xor(rs, 32);
          lrun[ti] += rs;
        }
        // O^T += V^T·P (kv permuted; V pre-permuted so A-frag is one b128)
        __builtin_amdgcn_s_setprio(1);
#pragma unroll
        for (int s = 0; s < 2; s++) {
          union { int4 i; bf16x8 v; } pf0, pf1;
          pf0.i = make_int4(pkv[0][2 * s][0], pkv[0][2 * s][1], pkv[0][2 * s + 1][0], pkv[0][2 * s + 1][1]);
          pf1.i = make_int4(pkv[1][2 * s][0], pkv[1][2 * s][1], pkv[1][2 * s + 1][0], pkv[1][2 * s + 1][1]);
#pragma unroll
          for (int hj = 0; hj < 8; hj++) {
            union { int4 i; bf16x8 v; } av;
            av.i = *(const int4*)&Vc[s * 4096 + (hj * 16 + c) * 32 + ((grp ^ sw) << 3)];
            oacc[0][hj] = __builtin_amdgcn_mfma_f32_16x16x32_bf16(av.v, pf0.v, oacc[0][hj], 0, 0, 0);
            oacc[1][hj] = __builtin_amdgcn_mfma_f32_16x16x32_bf16(av.v, pf1.v, oacc[1][hj], 0, 0, 0);
          }
        }
        __builtin_amdgcn_s_setprio(0);
      }
      __syncthreads();   // drains prefetch (issued a full compute ago) + buffer handoff
    }

    // epilogue: lane owns O^T[h][q=ti*16+c]; l is lane-local.
#pragma unroll
    for (int ti = 0; ti < 2; ti++) {
      float inv = 1.f / lrun[ti];
      int trow = t0 + w * 32 + ti * 16 + c;
#pragma unroll
      for (int hj = 0; hj < 8; hj++) {
        ushort4 o;
        o.x = f2bf(oacc[ti][hj][0] * inv);
        o.y = f2bf(oacc[ti][hj][1] * inv);
        o.z = f2bf(oacc[ti][hj][2] * inv);
        o.w = f2bf(oacc[ti][hj][3] * inv);
        *(ushort4*)&y[((size_t)(b * T_ + trow)) * HID_ + hq * HD_ + hj * 16 + grp * 4] = o;
      }
    }
  }
}

// ---------------- launcher ----------------
extern "C" void kernel_launch(void* const* d_in, const int* in_sizes, int n_in,
                              void* d_out, int out_size, void* d_ws, size_t ws_size,
                              hipStream_t stream) {
  const float* x    = (const float*)d_in[0];
  const float* cosb = (const float*)d_in[1];
  const float* sinb = (const float*)d_in[2];
  const float* Wq   = (const float*)d_in[3];
  const float* Wk   = (const float*)d_in[4];
  const float* Wv   = (const float*)d_in[5];
  const float* Wo   = (const float*)d_in[6];
  float* out = (float*)d_out;

  char* ws = (char*)d_ws;
  size_t off = 0;
  auto take = [&](size_t elems) {
    unsigned short* p = (unsigned short*)(ws + off);
    off += ((elems * 2 + 255) & ~(size_t)255);
    return p;
  };
  unsigned short* xb   = take((size_t)M_ * HID_);
  unsigned short* wqkv = take((size_t)NQKV_ * HID_);
  unsigned short* wob  = take((size_t)HID_ * HID_);
  unsigned short* qkv  = take((size_t)M_ * NQKV_);
  unsigned short* qb   = take((size_t)B_ * NH_ * T_ * HD_);
  unsigned short* kb   = take((size_t)B_ * NKV_ * T_ * HD_);
  unsigned short* vb   = take((size_t)B_ * NKV_ * T_ * HD_);
  unsigned short* vtb  = take((size_t)B_ * NKV_ * T_ * HD_);
  unsigned short* yb   = take((size_t)M_ * HID_);
  (void)ws_size; (void)in_sizes; (void)n_in; (void)out_size;

  cast_bf16<<<16384, 256, 0, stream>>>(x, xb, 4194304);
  cast_w<<<5120, 256, 0, stream>>>(Wq, Wk, Wv, wqkv);
  cast_bf16<<<4096, 256, 0, stream>>>(Wo, wob, 1048576);

  gemm256<1><<<dim3(10, 32), 512, 0, stream>>>(xb, wqkv, qkv, M_, NQKV_, HID_);
  rope_norm<<<8192, 256, 0, stream>>>(qkv, cosb, sinb, qb, kb, vb);
  transpose_v<<<dim3(32, 2, 8), 256, 0, stream>>>(vb, vtb);
  flash_attn<<<dim3(512), 256, 0, stream>>>(qb, kb, vtb, yb);
  gemm256<0><<<dim3(8, 32), 512, 0, stream>>>(yb, wob, out, M_, HID_, HID_);
}

// Round 7
// 450.745 us; speedup vs baseline: 1.7041x; 1.0183x over previous
//
#include <hip/hip_runtime.h>

// Problem constants (B,T,HID)=(4,2048,2048), heads 16, kv 2, hd 128.
#define B_    4
#define T_    2048
#define HID_  2048
#define NH_   16
#define NKV_  2
#define HD_   128
#define M_    (B_ * T_)      // 8192 rows
#define NQKV_ 2560           // 16*128 + 2*128 + 2*128

typedef __bf16 bf16x8 __attribute__((ext_vector_type(8)));
typedef float  f32x4  __attribute__((ext_vector_type(4)));

#define AS1 __attribute__((address_space(1)))
#define AS3 __attribute__((address_space(3)))

#if __has_builtin(__builtin_amdgcn_exp2f)
#define EXP2(x) __builtin_amdgcn_exp2f(x)
#else
#define EXP2(x) exp2f(x)
#endif

// async global->LDS, 16B per lane; LDS dest = wave-uniform base + lane*16
__device__ __forceinline__ void load_lds16(const void* g, void* l) {
  __builtin_amdgcn_global_load_lds((const AS1 unsigned int*)g,
                                   (AS3 unsigned int*)l, 16, 0, 0);
}

__device__ __forceinline__ unsigned short f2bf(float x) {
  union { float f; unsigned u; } a; a.f = x;
  unsigned r = a.u + 0x7fffu + ((a.u >> 16) & 1u);   // RNE
  return (unsigned short)(r >> 16);
}
__device__ __forceinline__ float bf2f(unsigned h) {
  union { unsigned u; float f; } a; a.u = h << 16;
  return a.f;
}
// pack two fp32 -> u32 of two bf16 (RTZ; P>=0, bias negligible)
__device__ __forceinline__ unsigned pk_rtz(float lo, float hi) {
  union { float f; unsigned u; } a, b; a.f = lo; b.f = hi;
  return (a.u >> 16) | (b.u & 0xffff0000u);
}

// ---------------- cast f32 -> bf16 (4 elems/thread) ----------------
__global__ __launch_bounds__(256) void cast_bf16(const float* __restrict__ in,
                                                 unsigned short* __restrict__ out,
                                                 int n4) {
  int i = blockIdx.x * 256 + threadIdx.x;
  if (i >= n4) return;
  float4 v = ((const float4*)in)[i];
  ushort4 o;
  o.x = f2bf(v.x); o.y = f2bf(v.y); o.z = f2bf(v.z); o.w = f2bf(v.w);
  ((ushort4*)out)[i] = o;
}

// merged Wq|Wk|Wv cast into contiguous wqkv (dest float4-index == i)
__global__ __launch_bounds__(256) void cast_w(const float* __restrict__ Wq,
                                              const float* __restrict__ Wk,
                                              const float* __restrict__ Wv,
                                              unsigned short* __restrict__ out) {
  int i = blockIdx.x * 256 + threadIdx.x;  // 5120*256 = 1310720 exact
  const float* src; int j;
  if (i < 1048576)      { src = Wq; j = i; }
  else if (i < 1179648) { src = Wk; j = i - 1048576; }
  else                  { src = Wv; j = i - 1179648; }
  float4 v = ((const float4*)src)[j];
  ushort4 o;
  o.x = f2bf(v.x); o.y = f2bf(v.y); o.z = f2bf(v.z); o.w = f2bf(v.w);
  ((ushort4*)out)[i] = o;
}

// ---------------- GEMM 256x256 (output projection): 8 waves, BK=64, 4-phase,
// counted vmcnt(6), dbuf LDS 128 KiB, XOR-swizzled. Per-block ~63 us measured
// (~55% util); grid 8x32 = 256 blocks = exactly 1 block/CU -> 1 clean round.
// MFMA clusters are ks-OUTERMOST so consecutive MFMAs hit different acc
// (dependent-reuse distance 8, not back-to-back); per-acc order unchanged
// (ks0 then ks1) -> bitwise-identical numerics.
template <int OUT_BF16>
__global__ __launch_bounds__(512, 1) void gemm256(const unsigned short* __restrict__ A,
                                                  const unsigned short* __restrict__ Bm,
                                                  void* __restrict__ C,
                                                  int M, int N, int K) {
  __shared__ __align__(16) unsigned short As[2][16384];  // [db][half*8192 + row*64 + u*8]
  __shared__ __align__(16) unsigned short Bs[2][16384];
  const int tid = threadIdx.x;
  const int w = tid >> 6, lane = tid & 63;
  const int wr = w >> 2, wc = w & 3;                 // 2M x 4N wave grid
  const int c = lane & 15, grp = lane >> 4;
  const int c7 = c & 7;
  const int m0 = blockIdx.y << 8, n0 = blockIdx.x << 8;
  const int srow = w * 8 + (lane >> 3);              // staging row within 64-row group
  const int su = ((lane & 7) ^ ((lane >> 3) & 7)) << 3;  // pre-swizzled source unit

  f32x4 acc[8][4] = {};
  const int nkt = K >> 6;                            // 32 for K=2048

  auto stA = [&](int h, int kt, int db) {
    const unsigned short* p = A + (size_t)(m0 + h * 128 + srow) * K + kt * 64 + su;
    load_lds16(p, &As[db][h * 8192 + (w * 8) * 64]);
    load_lds16(p + (size_t)64 * K, &As[db][h * 8192 + (64 + w * 8) * 64]);
  };
  auto stB = [&](int h, int kt, int db) {
    const unsigned short* p = Bm + (size_t)(n0 + h * 128 + srow) * K + kt * 64 + su;
    load_lds16(p, &Bs[db][h * 8192 + (w * 8) * 64]);
    load_lds16(p + (size_t)64 * K, &Bs[db][h * 8192 + (64 + w * 8) * 64]);
  };

  // prologue: kt0 fully + kt1 {B0,B1,A0}; vmcnt(6) -> kt0 resident
  stA(0, 0, 0); stA(1, 0, 0); stB(0, 0, 0); stB(1, 0, 0);
  if (nkt > 1) { stB(0, 1, 1); stB(1, 1, 1); stA(0, 1, 1); }
  asm volatile("s_waitcnt vmcnt(6)" ::: "memory");
  __builtin_amdgcn_s_barrier();

  const int Abase = wr * 8192;
  const int Bbase = (wc >> 1) * 8192 + ((wc & 1) * 64) * 64;

#define RDQ(arr, mtA, mtB)                                                          \
  _Pragma("unroll")                                                                 \
  for (int ks = 0; ks < 2; ks++) {                                                  \
    arr[0][ks] = *(const bf16x8*)&Ad[((mtA) * 16 + c) * 64 + (((ks << 2) + grp) ^ c7) * 8]; \
    arr[1][ks] = *(const bf16x8*)&Ad[((mtB) * 16 + c) * 64 + (((ks << 2) + grp) ^ c7) * 8]; \
  }
#define MMQ(arr, mt0)                                                               \
  __builtin_amdgcn_s_setprio(1);                                                    \
  _Pragma("unroll")                                                                 \
  for (int ks = 0; ks < 2; ks++)                                                    \
    _Pragma("unroll")                                                               \
    for (int i = 0; i < 2; i++)                                                     \
      _Pragma("unroll")                                                             \
      for (int nt = 0; nt < 4; nt++)                                                \
        acc[(mt0) + i][nt] = __builtin_amdgcn_mfma_f32_16x16x32_bf16(               \
            arr[i][ks], b_[nt][ks], acc[(mt0) + i][nt], 0, 0, 0);                   \
  __builtin_amdgcn_s_setprio(0);

  for (int kt = 0; kt < nkt; ++kt) {
    const int db = kt & 1;
    const unsigned short* Ad = &As[db][Abase];
    const unsigned short* Bd = &Bs[db][Bbase];
    bf16x8 b_[4][2], a01[2][2], a23[2][2], a45[2][2], a67[2][2];
    // ---- phase 1: read q0, B(8), q1; stage A1(kt+1); MFMA q0
    RDQ(a01, 0, 1)
#pragma unroll
    for (int nt = 0; nt < 4; nt++)
#pragma unroll
      for (int ks = 0; ks < 2; ks++)
        b_[nt][ks] = *(const bf16x8*)&Bd[(nt * 16 + c) * 64 + (((ks << 2) + grp) ^ c7) * 8];
    RDQ(a23, 2, 3)
    if (kt + 1 < nkt) stA(1, kt + 1, db ^ 1);
    __builtin_amdgcn_s_barrier();
    MMQ(a01, 0)
    __builtin_amdgcn_s_barrier();
    // ---- phase 2: read q2; stage B0(kt+2); MFMA q1
    RDQ(a45, 4, 5)
    if (kt + 2 < nkt) stB(0, kt + 2, db);
    __builtin_amdgcn_s_barrier();
    MMQ(a23, 2)
    __builtin_amdgcn_s_barrier();
    // ---- phase 3: read q3; stage B1(kt+2); MFMA q2
    RDQ(a67, 6, 7)
    if (kt + 2 < nkt) stB(1, kt + 2, db);
    __builtin_amdgcn_s_barrier();
    MMQ(a45, 4)
    __builtin_amdgcn_s_barrier();
    // ---- phase 4: stage A0(kt+2); counted vmcnt; MFMA q3
    if (kt + 2 < nkt) {
      stA(0, kt + 2, db);
      asm volatile("s_waitcnt vmcnt(6)" ::: "memory");
    } else {
      asm volatile("s_waitcnt vmcnt(0)" ::: "memory");
    }
    __builtin_amdgcn_s_barrier();
    MMQ(a67, 6)
    __builtin_amdgcn_s_barrier();
  }
#undef RDQ
#undef MMQ

  // epilogue: acc[mt][nt] -> row m0+wr*128+mt*16+grp*4+r, col n0+wc*64+nt*16+c
#pragma unroll
  for (int mt = 0; mt < 8; mt++)
#pragma unroll
    for (int nt = 0; nt < 4; nt++)
#pragma unroll
      for (int r = 0; r < 4; r++) {
        int row = m0 + wr * 128 + mt * 16 + grp * 4 + r;
        int col = n0 + wc * 64 + nt * 16 + c;
        float v = acc[mt][nt][r];
        if (OUT_BF16) ((unsigned short*)C)[(size_t)row * N + col] = f2bf(v);
        else          ((float*)C)[(size_t)row * N + col] = v;
      }
}

// ---------------- GEMM 256x128 (QKV): same discipline, HALF-width tile so the
// 8192x2560 grid becomes 20x32 = 640 blocks of ~32 us -> ~2.5-round makespan
// on 256 CUs instead of 256^2's forced 2 full rounds (320 blocks @ 1/CU was
// the QKV bottleneck: per-block ~63.5 us, makespan 127 us). LDS = 2x(32K A +
// 16K B) = 96 KiB. 2 phases/K-tile (16 MFMA each -> same per-MFMA barrier
// overhead as the 4-phase 256^2). Stage-ahead: A1(kt+1)@ph1, {B,A0}(kt+2)@ph2,
// steady vmcnt(4) (in flight: B,A0 of kt+2), never 0 until the tail.
// WAR-free: A0/B of kt+2 (same db as kt) are written only after kt's reads of
// those regions retired (reads complete before the ph1 post-MFMA barrier that
// precedes the ph2 stage issue).
template <int OUT_BF16>
__global__ __launch_bounds__(512, 1) void gemm256x128(const unsigned short* __restrict__ A,
                                                      const unsigned short* __restrict__ Bm,
                                                      void* __restrict__ C,
                                                      int M, int N, int K) {
  __shared__ __align__(16) unsigned short As[2][16384];  // 256 rows x 64, 32KB/buf
  __shared__ __align__(16) unsigned short Bs[2][8192];   // 128 rows x 64, 16KB/buf
  const int tid = threadIdx.x;
  const int w = tid >> 6, lane = tid & 63;
  const int wr = w >> 2, wc = w & 3;                 // 2M x 4N waves; per-wave 128x32
  const int c = lane & 15, grp = lane >> 4;
  const int c7 = c & 7;
  const int m0 = blockIdx.y << 8, n0 = blockIdx.x << 7;
  const int srow = w * 8 + (lane >> 3);
  const int su = ((lane & 7) ^ ((lane >> 3) & 7)) << 3;

  f32x4 acc[8][2] = {};
  const int nkt = K >> 6;                            // 32 for K=2048

  auto stA = [&](int h, int kt, int db) {
    const unsigned short* p = A + (size_t)(m0 + h * 128 + srow) * K + kt * 64 + su;
    load_lds16(p, &As[db][h * 8192 + (w * 8) * 64]);
    load_lds16(p + (size_t)64 * K, &As[db][h * 8192 + (64 + w * 8) * 64]);
  };
  auto stB = [&](int kt, int db) {
    const unsigned short* p = Bm + (size_t)(n0 + srow) * K + kt * 64 + su;
    load_lds16(p, &Bs[db][(w * 8) * 64]);
    load_lds16(p + (size_t)64 * K, &Bs[db][(64 + w * 8) * 64]);
  };

  // prologue: kt0 {A0,A1,B} + kt1 {B,A0}; vmcnt(4) -> kt0 resident
  stA(0, 0, 0); stA(1, 0, 0); stB(0, 0);
  if (nkt > 1) { stB(1, 1); stA(0, 1, 1); }
  asm volatile("s_waitcnt vmcnt(4)" ::: "memory");
  __builtin_amdgcn_s_barrier();

  const int Abase = wr * 8192;
  const int Bcol = wc * 32;

#define RDQ2(arr, mtA, mtB)                                                         \
  _Pragma("unroll")                                                                 \
  for (int ks = 0; ks < 2; ks++) {                                                  \
    arr[0][ks] = *(const bf16x8*)&Ad[((mtA) * 16 + c) * 64 + (((ks << 2) + grp) ^ c7) * 8]; \
    arr[1][ks] = *(const bf16x8*)&Ad[((mtB) * 16 + c) * 64 + (((ks << 2) + grp) ^ c7) * 8]; \
  }
#define MMQ2(q0, q1, mt0)                                                           \
  __builtin_amdgcn_s_setprio(1);                                                    \
  _Pragma("unroll")                                                                 \
  for (int ks = 0; ks < 2; ks++)                                                    \
    _Pragma("unroll")                                                               \
    for (int i = 0; i < 4; i++) {                                                   \
      bf16x8 av = (i < 2) ? q0[i][ks] : q1[i - 2][ks];                              \
      _Pragma("unroll")                                                             \
      for (int nt = 0; nt < 2; nt++)                                                \
        acc[(mt0) + i][nt] = __builtin_amdgcn_mfma_f32_16x16x32_bf16(               \
            av, b_[nt][ks], acc[(mt0) + i][nt], 0, 0, 0);                           \
    }                                                                               \
  __builtin_amdgcn_s_setprio(0);

  for (int kt = 0; kt < nkt; ++kt) {
    const int db = kt & 1;
    const unsigned short* Ad = &As[db][Abase];
    const unsigned short* Bd = &Bs[db][0];
    bf16x8 b_[2][2], a01[2][2], a23[2][2], a45[2][2], a67[2][2];
    // ---- phase 1: read a(mt0-3)[8] + b[4]; stage A1(kt+1); MFMA mt0-3
    RDQ2(a01, 0, 1)
#pragma unroll
    for (int nt = 0; nt < 2; nt++)
#pragma unroll
      for (int ks = 0; ks < 2; ks++)
        b_[nt][ks] = *(const bf16x8*)&Bd[(Bcol + nt * 16 + c) * 64 + (((ks << 2) + grp) ^ c7) * 8];
    RDQ2(a23, 2, 3)
    if (kt + 1 < nkt) stA(1, kt + 1, db ^ 1);
    __builtin_amdgcn_s_barrier();
    MMQ2(a01, a23, 0)
    __builtin_amdgcn_s_barrier();
    // ---- phase 2: read a(mt4-7)[8]; stage {B,A0}(kt+2); counted vmcnt; MFMA mt4-7
    RDQ2(a45, 4, 5)
    RDQ2(a67, 6, 7)
    if (kt + 2 < nkt) {
      stB(kt + 2, db);
      stA(0, kt + 2, db);
      asm volatile("s_waitcnt vmcnt(4)" ::: "memory");
    } else {
      asm volatile("s_waitcnt vmcnt(0)" ::: "memory");
    }
    __builtin_amdgcn_s_barrier();
    MMQ2(a45, a67, 4)
    __builtin_amdgcn_s_barrier();
  }
#undef RDQ2
#undef MMQ2

  // epilogue: acc[mt][nt] -> row m0+wr*128+mt*16+grp*4+r, col n0+wc*32+nt*16+c
#pragma unroll
  for (int mt = 0; mt < 8; mt++)
#pragma unroll
    for (int nt = 0; nt < 2; nt++)
#pragma unroll
      for (int r = 0; r < 4; r++) {
        int row = m0 + wr * 128 + mt * 16 + grp * 4 + r;
        int col = n0 + wc * 32 + nt * 16 + c;
        float v = acc[mt][nt][r];
        if (OUT_BF16) ((unsigned short*)C)[(size_t)row * N + col] = f2bf(v);
        else          ((float*)C)[(size_t)row * N + col] = v;
      }
}

// ---------------- RoPE + RMSNorm. One wave per head per (b,t).
// q additionally pre-scaled by attn_scale*log2(e) so flash's softmax uses exp2 directly.
__global__ __launch_bounds__(256) void rope_norm(const unsigned short* __restrict__ qkv,
                                                 const float* __restrict__ cosb,
                                                 const float* __restrict__ sinb,
                                                 unsigned short* __restrict__ qo,
                                                 unsigned short* __restrict__ ko,
                                                 unsigned short* __restrict__ vo) {
  const int m = blockIdx.x;
  const int b = m >> 11, t = m & 2047;
  const int w = threadIdx.x >> 6, lane = threadIdx.x & 63;
  const float cv = cosb[t * 64 + lane], sv = sinb[t * 64 + lane];
  const unsigned short* row = qkv + (size_t)m * NQKV_;
  const float QSCL = 0.08838834764831845f * 1.4426950408889634f;  // 1/sqrt(128)*log2(e)
  for (int hh = w; hh < 20; hh += 4) {
    if (hh < 18) {
      const int col0 = (hh < 16) ? hh * 128 : 2048 + (hh - 16) * 128;
      unsigned pr = *(const unsigned*)(row + col0 + 2 * lane);
      float xr = bf2f(pr & 0xffffu), xi = bf2f(pr >> 16);
      float orr = xr * cv - xi * sv;
      float oi  = xr * sv + xi * cv;
      float ss = orr * orr + oi * oi;
#pragma unroll
      for (int off = 1; off < 64; off <<= 1) ss += __shfl_xor(ss, off);
      float scl = rsqrtf(ss * (1.0f / 128.0f) + 1.1920929e-07f);  // fp32 eps
      if (hh < 16) {
        float s2 = scl * QSCL;
        unsigned out = (unsigned)f2bf(orr * s2) | ((unsigned)f2bf(oi * s2) << 16);
        *(unsigned*)(qo + (((size_t)(b * NH_ + hh)) * T_ + t) * HD_ + 2 * lane) = out;
      } else {
        unsigned out = (unsigned)f2bf(orr * scl) | ((unsigned)f2bf(oi * scl) << 16);
        *(unsigned*)(ko + (((size_t)(b * NKV_ + (hh - 16))) * T_ + t) * HD_ + 2 * lane) = out;
      }
    } else {
      const int gg = hh - 18;
      unsigned pr = *(const unsigned*)(row + 2304 + gg * 128 + 2 * lane);
      *(unsigned*)(vo + (((size_t)(b * NKV_ + gg)) * T_ + t) * HD_ + 2 * lane) = pr;
    }
  }
}

// ---------------- V transpose: (bg, T, HD) -> (bg, HD, T), 64x64 LDS tiles.
// Output columns are PERMUTED within each 32-kv chunk so flash's PV A-fragment
// is one contiguous b128: position p=8g+4a+b holds kv=16a+4g+b.
__global__ __launch_bounds__(256) void transpose_v(const unsigned short* __restrict__ v,
                                                   unsigned short* __restrict__ vt) {
  __shared__ unsigned short tile[64][65];
  const int bg = blockIdx.z;
  const int t0 = blockIdx.x << 6, h0 = blockIdx.y << 6;
  const unsigned short* src = v + (size_t)bg * T_ * HD_;
  unsigned short* dst = vt + (size_t)bg * T_ * HD_;
  const int tid = threadIdx.x;
  const int rr = tid >> 4, cc = (tid & 15) << 2;
  const int u = (cc >> 2) & 7;
  const int cp = (cc & 32) + 16 * (u & 1) + 4 * ((u >> 1) & 3);  // source col for dst col cc
#pragma unroll
  for (int it = 0; it < 4; it++) {
    int r = rr + it * 16;
    ushort4 d = *(const ushort4*)(src + (size_t)(t0 + r) * HD_ + h0 + cc);
    tile[r][cc + 0] = d.x; tile[r][cc + 1] = d.y;
    tile[r][cc + 2] = d.z; tile[r][cc + 3] = d.w;
  }
  __syncthreads();
#pragma unroll
  for (int it = 0; it < 4; it++) {
    int r = rr + it * 16;
    ushort4 d;
    d.x = tile[cp + 0][r]; d.y = tile[cp + 1][r];
    d.z = tile[cp + 2][r]; d.w = tile[cp + 3][r];
    *(ushort4*)(dst + (size_t)(h0 + r) * T_ + t0 + cc) = d;
  }
}

// ---------------- Flash attention v6: uniform-work paired blocks.
// Causal tile i costs 2i+2 64-kv chunks, so pair (i, 15-i) costs exactly 34
// chunks for EVERY pair. One block runs both tiles of a pair as two
// sequential phases (same (b,hq) -> same K/V stream; phase-1 chunks are
// L2-hot from phase 0). Grid = 512 uniform blocks = exactly the 2-block/CU
// LDS capacity (64 KiB each) -> every CU holds 2 identical-work blocks:
// constant 8 active waves/CU, zero finish skew, zero dispatch tail.
__global__ __launch_bounds__(256, 2) void flash_attn(const unsigned short* __restrict__ q,
                                                     const unsigned short* __restrict__ k,
                                                     const unsigned short* __restrict__ vt,
                                                     unsigned short* __restrict__ y) {
  __shared__ __align__(16) unsigned short Kb[2][8192];  // [buf][dc4][kv64][d-unit swz]
  __shared__ __align__(16) unsigned short Vb[2][8192];  // [buf][ks2][h128][kv-unit swz]
  const int tid = threadIdx.x;
  const int w = tid >> 6, lane = tid & 63;
  const int c = lane & 15, grp = lane >> 4;
  const int lr = lane >> 2;
  const int sw = (c >> 1) & 3;
  const int su = (((lane & 3) ^ ((lr >> 1) & 3)) << 3);

  const int idx = blockIdx.x;            // 0..511
  const int p  = idx & 7;                // pair id: tiles {15-p, p}
  const int hq = (idx >> 3) & 15;
  const int b  = idx >> 7;
  const int g  = hq >> 3;

  const unsigned short* kbase  = k  + ((size_t)(b * NKV_ + g)) * T_ * HD_;
  const unsigned short* vtbase = vt + ((size_t)(b * NKV_ + g)) * HD_ * T_;

  auto stage = [&](int s0, int bb) {
    const unsigned short* kp = kbase + (size_t)(s0 + w * 16 + lr) * HD_ + su;
#pragma unroll
    for (int dc = 0; dc < 4; dc++)
      load_lds16(kp + dc * 32, &Kb[bb][dc * 2048 + (w * 16) * 32]);
    const unsigned short* vp = vtbase + s0 + su;
#pragma unroll
    for (int ks = 0; ks < 2; ks++)
#pragma unroll
      for (int jj = 0; jj < 2; jj++)
        load_lds16(vp + (size_t)(w * 32 + jj * 16 + lr) * T_ + ks * 32,
                   &Vb[bb][ks * 4096 + (w * 32 + jj * 16) * 32]);
  };

  for (int ph = 0; ph < 2; ph++) {
    const int tile = ph ? p : (15 - p);    // heavy phase first
    const int t0 = tile << 7;
    const int t0w = t0 + w * 32;
    const unsigned short* qbase = q + (((size_t)(b * NH_ + hq)) * T_ + t0) * HD_;

    // Q fragments (pre-scaled by scale*log2e): B-operand layout, rows q
    bf16x8 qf[2][4];
#pragma unroll
    for (int ti = 0; ti < 2; ti++)
#pragma unroll
      for (int ks = 0; ks < 4; ks++)
        qf[ti][ks] = *(const bf16x8*)(qbase + (size_t)(w * 32 + ti * 16 + c) * HD_ + ks * 32 + grp * 8);

    f32x4 oacc[2][8] = {};            // O^T: row h=hj*16+grp*4+r, col q=ti*16+c
    float mrun[2], lrun[2];
    mrun[0] = mrun[1] = -__builtin_inff();
    lrun[0] = lrun[1] = 0.f;

    const int nch = (t0 >> 6) + 2;
    stage(0, 0);                         // prior phase's final barrier guards the buffer
    __syncthreads();                     // chunk 0 resident
    for (int ic = 0; ic < nch; ic++) {
      const int s0 = ic << 6, bb = ic & 1;
      if (ic + 1 < nch) stage((ic + 1) << 6, bb ^ 1);  // async prefetch, drained at loop-end barrier
      if (s0 <= t0w + 31) {              // wave has unmasked work in this chunk
        const unsigned short* Kc = Kb[bb];
        const unsigned short* Vc = Vb[bb];
        // S^T = K·Q^T : lane holds P[q=ti*16+c][kv=kvt*16+grp*4+r] (log2 domain)
        f32x4 st[2][4] = {};
        __builtin_amdgcn_s_setprio(1);
#pragma unroll
        for (int s = 0; s < 4; s++)
#pragma unroll
          for (int kvt = 0; kvt < 4; kvt++) {
            bf16x8 ak = *(const bf16x8*)&Kc[s * 2048 + (kvt * 16 + c) * 32 + ((grp ^ sw) << 3)];
            st[0][kvt] = __builtin_amdgcn_mfma_f32_16x16x32_bf16(ak, qf[0][s], st[0][kvt], 0, 0, 0);
            st[1][kvt] = __builtin_amdgcn_mfma_f32_16x16x32_bf16(ak, qf[1][s], st[1][kvt], 0, 0, 0);
          }
        __builtin_amdgcn_s_setprio(0);
        if (s0 + 63 > t0w) {             // diagonal chunk: causal mask
#pragma unroll
          for (int ti = 0; ti < 2; ti++)
#pragma unroll
            for (int kvt = 0; kvt < 4; kvt++)
#pragma unroll
              for (int r = 0; r < 4; r++) {
                int kv = s0 + kvt * 16 + grp * 4 + r;
                int qq = t0w + ti * 16 + c;
                if (kv > qq) st[ti][kvt][r] = -__builtin_inff();
              }
        }
        // online softmax per q-column (lane-local + cross-grp butterfly).
        // defer-max (T13): skip the oacc rescale unless some column's max
        // grew >8 (log2 domain; P bounded by 2^8, fine in f32 accum).
        unsigned pkv[2][4][2];
#pragma unroll
        for (int ti = 0; ti < 2; ti++) {
          float rm = st[ti][0][0];
#pragma unroll
          for (int kvt = 0; kvt < 4; kvt++)
#pragma unroll
            for (int r = 0; r < 4; r++) rm = fmaxf(rm, st[ti][kvt][r]);
          rm = fmaxf(rm, __shfl_xor(rm, 16));
          rm = fmaxf(rm, __shfl_xor(rm, 32));
          if (!__all(rm <= mrun[ti] + 8.f)) {
            float mnew = fmaxf(mrun[ti], rm);
            float alpha = EXP2(mrun[ti] - mnew);
            mrun[ti] = mnew;
            lrun[ti] *= alpha;
#pragma unroll
            for (int hj = 0; hj < 8; hj++)
#pragma unroll
              for (int r = 0; r < 4; r++) oacc[ti][hj][r] *= alpha;
          }
          const float m0 = mrun[ti];
          float rs = 0.f;
#pragma unroll
          for (int kvt = 0; kvt < 4; kvt++) {
            float p0 = EXP2(st[ti][kvt][0] - m0);
            float p1 = EXP2(st[ti][kvt][1] - m0);
            float p2 = EXP2(st[ti][kvt][2] - m0);
            float p3 = EXP2(st[ti][kvt][3] - m0);
            rs += (p0 + p1) + (p2 + p3);
            pkv[ti][kvt][0] = pk_rtz(p0, p1);
            pkv[ti][kvt][1] = pk_rtz(p2, p3);
          }
          rs += __shfl_xor(rs, 16);
          rs += __shfl_xor(rs, 32);
          lrun[ti] += rs;
        }
        // O^T += V^T·P (kv permuted; V pre-permuted so A-frag is one b128)
        __builtin_amdgcn_s_setprio(1);
#pragma unroll
        for (int s = 0; s < 2; s++) {
          union { int4 i; bf16x8 v; } pf0, pf1;
          pf0.i = make_int4(pkv[0][2 * s][0], pkv[0][2 * s][1], pkv[0][2 * s + 1][0], pkv[0][2 * s + 1][1]);
          pf1.i = make_int4(pkv[1][2 * s][0], pkv[1][2 * s][1], pkv[1][2 * s + 1][0], pkv[1][2 * s + 1][1]);
#pragma unroll
          for (int hj = 0; hj < 8; hj++) {
            union { int4 i; bf16x8 v; } av;
            av.i = *(const int4*)&Vc[s * 4096 + (hj * 16 + c) * 32 + ((grp ^ sw) << 3)];
            oacc[0][hj] = __builtin_amdgcn_mfma_f32_16x16x32_bf16(av.v, pf0.v, oacc[0][hj], 0, 0, 0);
            oacc[1][hj] = __builtin_amdgcn_mfma_f32_16x16x32_bf16(av.v, pf1.v, oacc[1][hj], 0, 0, 0);
          }
        }
        __builtin_amdgcn_s_setprio(0);
      }
      __syncthreads();   // drains prefetch (issued a full compute ago) + buffer handoff
    }

    // epilogue: lane owns O^T[h][q=ti*16+c]; l is lane-local.
#pragma unroll
    for (int ti = 0; ti < 2; ti++) {
      float inv = 1.f / lrun[ti];
      int trow = t0 + w * 32 + ti * 16 + c;
#pragma unroll
      for (int hj = 0; hj < 8; hj++) {
        ushort4 o;
        o.x = f2bf(oacc[ti][hj][0] * inv);
        o.y = f2bf(oacc[ti][hj][1] * inv);
        o.z = f2bf(oacc[ti][hj][2] * inv);
        o.w = f2bf(oacc[ti][hj][3] * inv);
        *(ushort4*)&y[((size_t)(b * T_ + trow)) * HID_ + hq * HD_ + hj * 16 + grp * 4] = o;
      }
    }
  }
}

// ---------------- launcher ----------------
extern "C" void kernel_launch(void* const* d_in, const int* in_sizes, int n_in,
                              void* d_out, int out_size, void* d_ws, size_t ws_size,
                              hipStream_t stream) {
  const float* x    = (const float*)d_in[0];
  const float* cosb = (const float*)d_in[1];
  const float* sinb = (const float*)d_in[2];
  const float* Wq   = (const float*)d_in[3];
  const float* Wk   = (const float*)d_in[4];
  const float* Wv   = (const float*)d_in[5];
  const float* Wo   = (const float*)d_in[6];
  float* out = (float*)d_out;

  char* ws = (char*)d_ws;
  size_t off = 0;
  auto take = [&](size_t elems) {
    unsigned short* p = (unsigned short*)(ws + off);
    off += ((elems * 2 + 255) & ~(size_t)255);
    return p;
  };
  unsigned short* xb   = take((size_t)M_ * HID_);
  unsigned short* wqkv = take((size_t)NQKV_ * HID_);
  unsigned short* wob  = take((size_t)HID_ * HID_);
  unsigned short* qkv  = take((size_t)M_ * NQKV_);
  unsigned short* qb   = take((size_t)B_ * NH_ * T_ * HD_);
  unsigned short* kb   = take((size_t)B_ * NKV_ * T_ * HD_);
  unsigned short* vb   = take((size_t)B_ * NKV_ * T_ * HD_);
  unsigned short* vtb  = take((size_t)B_ * NKV_ * T_ * HD_);
  unsigned short* yb   = take((size_t)M_ * HID_);
  (void)ws_size; (void)in_sizes; (void)n_in; (void)out_size;

  cast_bf16<<<16384, 256, 0, stream>>>(x, xb, 4194304);
  cast_w<<<5120, 256, 0, stream>>>(Wq, Wk, Wv, wqkv);
  cast_bf16<<<4096, 256, 0, stream>>>(Wo, wob, 1048576);

  gemm256x128<1><<<dim3(20, 32), 512, 0, stream>>>(xb, wqkv, qkv, M_, NQKV_, HID_);
  rope_norm<<<8192, 256, 0, stream>>>(qkv, cosb, sinb, qb, kb, vb);
  transpose_v<<<dim3(32, 2, 8), 256, 0, stream>>>(vb, vtb);
  flash_attn<<<dim3(512), 256, 0, stream>>>(qb, kb, vtb, yb);
  gemm256<0><<<dim3(8, 32), 512, 0, stream>>>(yb, wob, out, M_, HID_, HID_);
}